// Round 6
// baseline (27175.992 us; speedup 1.0000x reference)
//
#include <hip/hip_runtime.h>
#include <hip/hip_bf16.h>
#include <cstdint>

typedef __hip_bfloat16 bf16;
typedef unsigned short u16;

__device__ __forceinline__ float tofloat(float x){ return x; }
__device__ __forceinline__ float tofloat(bf16 x){ return __bfloat162float(x); }
__device__ __forceinline__ float b2f(u16 a){ return __uint_as_float(((unsigned)a) << 16); }
__device__ __forceinline__ u16 f2b(float f){           // round-to-nearest-even
    unsigned u = __float_as_uint(f);
    return (u16)((u + 0x7FFFu + ((u >> 16) & 1u)) >> 16);
}
__device__ __forceinline__ void store4(float* p, float a, float b, float c, float d){
    float4 v = make_float4(a, b, c, d); *(float4*)p = v;
}
__device__ __forceinline__ void store4(u16* p, float a, float b, float c, float d){
    ushort4 v; v.x = f2b(a); v.y = f2b(b); v.z = f2b(c); v.w = f2b(d);
    *(ushort4*)p = v;
}

static inline int divup(long a, long b){ return (int)((a + b - 1) / b); }

// ---------------- input dtype detection -------------------------------------
__global__ void zero_int(int* p){ *p = 0; }

__global__ void detect_f32(const u16* __restrict__ h, long n, int* flag)
{
    long i = (long)blockIdx.x * blockDim.x + threadIdx.x;
    long st = (long)gridDim.x * blockDim.x;
    int c = 0;
    for (; i < n; i += st)
        if (((h[i] >> 7) & 0xFF) == 0xFF) c++;
    if (c) atomicAdd(flag, c);
}

__global__ void conv_in(const void* __restrict__ src, float* __restrict__ dst,
                        long n, const int* __restrict__ flagp)
{
    bool f32 = (*flagp != 0);
    long i = (long)blockIdx.x * blockDim.x + threadIdx.x;
    long st = (long)gridDim.x * blockDim.x;
    for (; i < n; i += st)
        dst[i] = f32 ? ((const float*)src)[i] : tofloat(((const bf16*)src)[i]);
}

// ---------------- 64x64-tile GEMM, 256 thr, 4x4 micro-tile ------------------
// C[M,N] = A[M,K] @ B[K,N].  AM: 0 = A fp32, 1 = A bf16(u16), 2 = dual.
// TC: float or u16 (bf16 out). Optional C2 (fp32) = acc * dinv[r]^2 (GCN self).
// K must be a multiple of 16; N a multiple of 64. Batch via blockIdx.z.
template<int AM, typename TC>
__global__ __launch_bounds__(256)
void gemm64(const void* __restrict__ A_, int lda,
            const float* __restrict__ B, int ldb,
            TC* __restrict__ C, int ldc,
            int M, int N, int K, long sB, long sC,
            const int* __restrict__ flagp,
            const float* __restrict__ dinvp, float* __restrict__ C2)
{
    bool af32 = (AM == 0);
    if (AM == 2) af32 = (*flagp != 0);
    const float* Af = (const float*)A_;
    const u16*   Au = (const u16*)A_;
    const float* Bp = B + (long)blockIdx.z * sB;
    TC*          Cp = C + (long)blockIdx.z * sC;

    __shared__ float As[16][68];
    __shared__ float Bs[16][68];

    const int tid = threadIdx.x;
    const int row0 = blockIdx.x * 64, col0 = blockIdx.y * 64;

    float acc[4][4];
#pragma unroll
    for (int i = 0; i < 4; i++)
#pragma unroll
        for (int j = 0; j < 4; j++) acc[i][j] = 0.f;

    const int ar = tid >> 2;            // 0..63 A row
    const int ak = (tid & 3) * 4;       // k offset 0,4,8,12
    const int bk = tid >> 4;            // 0..15 B k
    const int bc = (tid & 15) * 4;      // col offset 0..60
    const int ty4 = (tid >> 4) * 4, tx4 = (tid & 15) * 4;

    for (int k0 = 0; k0 < K; k0 += 16) {
        // stage A: 64 rows x 16 k
        {
            int row = row0 + ar;
            float x0 = 0.f, x1 = 0.f, x2 = 0.f, x3 = 0.f;
            if (row < M) {
                long base = (long)row * lda + k0 + ak;
                if (af32) {
                    float4 v = *(const float4*)(Af + base);
                    x0 = v.x; x1 = v.y; x2 = v.z; x3 = v.w;
                } else {
                    ushort4 u = *(const ushort4*)(Au + base);
                    x0 = b2f(u.x); x1 = b2f(u.y); x2 = b2f(u.z); x3 = b2f(u.w);
                }
            }
            As[ak + 0][ar] = x0; As[ak + 1][ar] = x1;
            As[ak + 2][ar] = x2; As[ak + 3][ar] = x3;
        }
        // stage B: 16 k x 64 cols
        {
            int c = col0 + bc;
            float4 v = make_float4(0.f, 0.f, 0.f, 0.f);
            if (c < N) v = *(const float4*)(Bp + (long)(k0 + bk) * ldb + c);
            *(float4*)&Bs[bk][bc] = v;
        }
        __syncthreads();
#pragma unroll
        for (int k = 0; k < 16; k++) {
            float4 a = *(const float4*)&As[k][ty4];
            float4 b = *(const float4*)&Bs[k][tx4];
            acc[0][0] += a.x * b.x; acc[0][1] += a.x * b.y; acc[0][2] += a.x * b.z; acc[0][3] += a.x * b.w;
            acc[1][0] += a.y * b.x; acc[1][1] += a.y * b.y; acc[1][2] += a.y * b.z; acc[1][3] += a.y * b.w;
            acc[2][0] += a.z * b.x; acc[2][1] += a.z * b.y; acc[2][2] += a.z * b.z; acc[2][3] += a.z * b.w;
            acc[3][0] += a.w * b.x; acc[3][1] += a.w * b.y; acc[3][2] += a.w * b.z; acc[3][3] += a.w * b.w;
        }
        __syncthreads();
    }

    int c = col0 + tx4;
#pragma unroll
    for (int i = 0; i < 4; i++) {
        int r = row0 + ty4 + i;
        if (r < M && c < N) {
            store4(&Cp[(long)r * ldc + c], acc[i][0], acc[i][1], acc[i][2], acc[i][3]);
            if (C2) {
                float dv = dinvp[r]; dv *= dv;
                store4(&C2[(long)r * ldc + c],
                       acc[i][0] * dv, acc[i][1] * dv, acc[i][2] * dv, acc[i][3] * dv);
            }
        }
    }
}

// ---------------- utility ---------------------------------------------------
__global__ void fillf(float* p, long n, float v)
{
    long i = (long)blockIdx.x * blockDim.x + threadIdx.x;
    long st = (long)gridDim.x * blockDim.x;
    for (; i < n; i += st) p[i] = v;
}

// ---------------- batch-norm (per-column, gamma=1 beta=0) -------------------
__global__ void colstats(const float* __restrict__ X, int M, int N,
                         float* __restrict__ s1, float* __restrict__ s2)
{
    int j = threadIdx.x;
    if (j >= N) return;
    int rows = (M + gridDim.x - 1) / gridDim.x;
    int r0 = blockIdx.x * rows;
    int r1 = min(M, r0 + rows);
    float a = 0.f, b = 0.f;
    for (int i = r0; i < r1; i++) {
        float v = X[(long)i * N + j];
        a += v; b += v * v;
    }
    atomicAdd(&s1[j], a);
    atomicAdd(&s2[j], b);
}

__global__ void bn_finalize(float* s1, float* s2, int N, int M)
{
    int j = blockIdx.x * blockDim.x + threadIdx.x;
    if (j >= N) return;
    float mean = s1[j] / (float)M;
    float var  = fmaxf(s2[j] / (float)M - mean * mean, 0.f);
    s1[j] = mean;
    s2[j] = rsqrtf(var + 1e-5f);
}

__global__ void bn_apply(float* X, long total, int mask,
                         const float* __restrict__ s1, const float* __restrict__ s2,
                         int relu)
{
    long i = (long)blockIdx.x * blockDim.x + threadIdx.x;
    long st = (long)gridDim.x * blockDim.x;
    for (; i < total; i += st) {
        int j = (int)(i & mask);
        float y = (X[i] - s1[j]) * s2[j];
        if (relu) y = fmaxf(y, 0.f);
        X[i] = y;
    }
}

// BN+ReLU fp32 chunk [M,64] -> bf16 dst[n*128 + c0 + f]
__global__ void bn_chunk_bf16(const float* __restrict__ X, long total,
                              const float* __restrict__ s1, const float* __restrict__ s2,
                              u16* __restrict__ dst, int c0)
{
    long i = (long)blockIdx.x * blockDim.x + threadIdx.x;
    long st = (long)gridDim.x * blockDim.x;
    for (; i < total; i += st) {
        long n = i >> 6;
        int  f = (int)(i & 63);
        float y = fmaxf((X[i] - s1[f]) * s2[f], 0.f);
        dst[n * 128 + c0 + f] = f2b(y);
    }
}

// ---------------- GCN pieces ------------------------------------------------
__global__ void deg_count(const int* __restrict__ dst, long E, float* deg)
{
    long i = (long)blockIdx.x * blockDim.x + threadIdx.x;
    long st = (long)gridDim.x * blockDim.x;
    for (; i < E; i += st) atomicAdd(&deg[dst[i]], 1.0f);
}

__global__ void rsqrt_inplace(float* p, long n)
{
    long i = (long)blockIdx.x * blockDim.x + threadIdx.x;
    long st = (long)gridDim.x * blockDim.x;
    for (; i < n; i += st) p[i] = rsqrtf(fmaxf(p[i], 1.0f));
}

// edge scatter, h bf16 [NM,64]; item = edge x quarter (16 floats)
__global__ void gcn_edge4(const u16* __restrict__ hb, const float* __restrict__ dinv,
                          const int* __restrict__ src, const int* __restrict__ dst,
                          long items, float* __restrict__ out)
{
    long i = (long)blockIdx.x * blockDim.x + threadIdx.x;
    long st = (long)gridDim.x * blockDim.x;
    for (; i < items; i += st) {
        long e = i >> 2; int q = (int)(i & 3);
        int s = src[e], d = dst[e];
        float nrm = dinv[s] * dinv[d];
        const ushort4* hp = (const ushort4*)(hb + (long)s * 64 + q * 16);
        float* o = out + (long)d * 64 + q * 16;
#pragma unroll
        for (int t = 0; t < 4; t++) {
            ushort4 u = hp[t];
            atomicAdd(o + t * 4 + 0, b2f(u.x) * nrm);
            atomicAdd(o + t * 4 + 1, b2f(u.y) * nrm);
            atomicAdd(o + t * 4 + 2, b2f(u.z) * nrm);
            atomicAdd(o + t * 4 + 3, b2f(u.w) * nrm);
        }
    }
}

// ---------------- pooling ---------------------------------------------------
__global__ void pool_cnt(const int* __restrict__ batch, long n, float* cnt)
{
    long i = (long)blockIdx.x * blockDim.x + threadIdx.x;
    long st = (long)gridDim.x * blockDim.x;
    for (; i < n; i += st) atomicAdd(&cnt[batch[i]], 1.0f);
}

// BIG fp32 [NM,64] -> gout[batch*256 + c0 + ...]; item = node x quarter
__global__ void pool_sum4(const float* __restrict__ g, const int* __restrict__ batch,
                          long items, float* __restrict__ sums, int c0)
{
    long i = (long)blockIdx.x * blockDim.x + threadIdx.x;
    long st = (long)gridDim.x * blockDim.x;
    for (; i < items; i += st) {
        long n = i >> 2; int q = (int)(i & 3);
        int b = batch[n];
        const float4* gp = (const float4*)(g + n * 64 + q * 16);
        float* o = sums + (long)b * 256 + c0 + q * 16;
#pragma unroll
        for (int t = 0; t < 4; t++) {
            float4 v = gp[t];
            atomicAdd(o + t * 4 + 0, v.x);
            atomicAdd(o + t * 4 + 1, v.y);
            atomicAdd(o + t * 4 + 2, v.z);
            atomicAdd(o + t * 4 + 3, v.w);
        }
    }
}

__global__ void pool_div(float* sums, const float* __restrict__ cnt, long total, int lg)
{
    long i = (long)blockIdx.x * blockDim.x + threadIdx.x;
    long st = (long)gridDim.x * blockDim.x;
    for (; i < total; i += st) sums[i] /= fmaxf(cnt[i >> lg], 1.0f);
}

// ---------------- attention fusion (one 128-thread block per drug) ----------
__global__ void attention_fuse(const float* __restrict__ go, const float* __restrict__ fpv,
                               const float* __restrict__ W1, const float* __restrict__ B1,
                               const float* __restrict__ W2,
                               float* __restrict__ emb, float* __restrict__ beta_out)
{
    int d = blockIdx.x;
    int t = threadIdx.x;
    __shared__ float z[2][256];
    __shared__ float red[128];
    for (int c = t; c < 256; c += 128) {
        z[0][c] = go[(long)d * 256 + c];
        z[1][c] = fpv[(long)d * 256 + c];
    }
    __syncthreads();
    float s[2];
    for (int v = 0; v < 2; v++) {
        float acc = B1[t];
        for (int k = 0; k < 256; k++) acc += z[v][k] * W1[k * 128 + t];
        red[t] = tanhf(acc) * W2[t];
        __syncthreads();
        for (int off = 64; off > 0; off >>= 1) {
            if (t < off) red[t] += red[t + off];
            __syncthreads();
        }
        s[v] = red[0];
        __syncthreads();
    }
    float m = fmaxf(s[0], s[1]);
    float e0 = expf(s[0] - m), e1 = expf(s[1] - m);
    float inv = 1.0f / (e0 + e1);
    float b0 = e0 * inv, b1 = e1 * inv;
    for (int c = t; c < 256; c += 128)
        emb[(long)d * 256 + c] = b0 * z[0][c] + b1 * z[1][c];
    if (t == 0) {
        beta_out[d * 2 + 0] = b0;
        beta_out[d * 2 + 1] = b1;
    }
}

// ---------------- RGCN pieces -----------------------------------------------
__global__ void kg_cnt(const int* __restrict__ dst, const int* __restrict__ et,
                       long E, int NKG, float* cnt)
{
    long i = (long)blockIdx.x * blockDim.x + threadIdx.x;
    long st = (long)gridDim.x * blockDim.x;
    for (; i < E; i += st) atomicAdd(&cnt[(long)et[i] * NKG + dst[i]], 1.0f);
}

// hr fp32 [8,NKG,64]; item = edge x quarter
__global__ void rgcn_edge4(const float* __restrict__ hr, const int* __restrict__ src,
                           const int* __restrict__ dst, const int* __restrict__ et,
                           const float* __restrict__ cnt, long items,
                           int NKG, float* __restrict__ out, int ldout, int c0)
{
    long i = (long)blockIdx.x * blockDim.x + threadIdx.x;
    long st = (long)gridDim.x * blockDim.x;
    for (; i < items; i += st) {
        long e = i >> 2; int q = (int)(i & 3);
        int r = et[e], s = src[e], d = dst[e];
        float nrm = 1.0f / fmaxf(cnt[(long)r * NKG + d], 1.0f);
        const float4* hp = (const float4*)(hr + ((long)r * NKG + s) * 64 + q * 16);
        float* o = out + (long)d * ldout + c0 + q * 16;
#pragma unroll
        for (int t = 0; t < 4; t++) {
            float4 v = hp[t];
            atomicAdd(o + t * 4 + 0, v.x * nrm);
            atomicAdd(o + t * 4 + 1, v.y * nrm);
            atomicAdd(o + t * 4 + 2, v.z * nrm);
            atomicAdd(o + t * 4 + 3, v.w * nrm);
        }
    }
}

// ---------------- final linear + log_softmax (fp32 out) ---------------------
__global__ void logits_out(const float* __restrict__ x4, const float* __restrict__ w,
                           const float* __restrict__ b, float* __restrict__ out, int NKG)
{
    int i = blockIdx.x * blockDim.x + threadIdx.x;
    if (i >= NKG) return;
    float a0 = b[0], a1 = b[1];
    for (int k = 0; k < 64; k++) {
        float v = x4[(long)i * 64 + k];
        a0 += v * w[k * 2 + 0];
        a1 += v * w[k * 2 + 1];
    }
    float m = fmaxf(a0, a1);
    float lse = m + logf(expf(a0 - m) + expf(a1 - m));
    out[i * 2 + 0] = a0 - lse;
    out[i * 2 + 1] = a1 - lse;
}

// ============================================================================
extern "C" void kernel_launch(void* const* d_in, const int* in_sizes, int n_in,
                              void* d_out, int out_size, void* d_ws, size_t ws_size,
                              hipStream_t stream)
{
    (void)in_sizes; (void)n_in; (void)out_size; (void)ws_size;
    const int ND = 4096, NM = 131072, NKG = 9510, NGENE = 5414;
    const long EM = 524288, EK = 524288;

    const void* fp_data = d_in[0];
    const void* mol_x   = d_in[1];
    const int*  mol_batch = (const int*)d_in[2];
    const int*  mol_ei  = (const int*)d_in[3];
    const int*  kg_ei   = (const int*)d_in[4];
    const int*  kg_et   = (const int*)d_in[5];

    const int* mol_src = mol_ei;
    const int* mol_dst = mol_ei + EM;
    const int* kg_src  = kg_ei;
    const int* kg_dst  = kg_ei + EK;

    float* out_ls   = (float*)d_out;          // [9510,2] fp32
    float* out_beta = (float*)d_out + 19020;  // [4096,2,1] fp32

    // ---- workspace carve (~100 MB; big regions time-shared) ----
    char* wp = (char*)d_ws;
    auto carve = [&](size_t bytes) { char* p = wp; wp += (bytes + 255) & ~(size_t)255; return p; };
    float* stats = (float*)carve(4096);                    // s1 | s2 at +512
    int*   flag  = (int*)carve(256);
    float* dinv  = (float*)carve((size_t)NM * 4);
    float* cntP  = (float*)carve((size_t)ND * 4);
    float* cntK  = (float*)carve((size_t)8 * NKG * 4);
    float* Wpool = (float*)carve((size_t)1630000 * 4);     // 6.5 MB fp32 weights
    float* fpb   = (float*)carve((size_t)ND * 256 * 4);    // 4.2 MB
    float* gout  = (float*)carve((size_t)ND * 256 * 4);    // 4.2 MB
    char*  REG1  = carve((size_t)NM * 128 * 2);            // 33.6 MB: fp1 / G1(bf16) / xkg..x4
    char*  REG2  = carve((size_t)NM * 64 * 4);             // 33.6 MB: BIG / HR
    u16*   HB    = (u16*)carve((size_t)NM * 64 * 2);       // 16.8 MB: h chunk (bf16)

    float* fp1 = (float*)REG1;                 // [4096,512] fp phase
    u16*   G1  = (u16*)REG1;                   // [NM,128] bf16 mol phase
    float* xkg = (float*)REG1;                 // RGCN phase (26.8 MB total)
    float* x2  = xkg + (size_t)NKG * 256;
    float* x3  = x2  + (size_t)NKG * 256;
    float* x4  = x3  + (size_t)NKG * 128;
    float* BIG = (float*)REG2;                 // [NM,64] fp32 scatter target
    float* HR  = (float*)REG2;                 // [8,NKG,64] fp32 RGCN messages

    // ---- dtype detection + parameter conversion to fp32 ----
    zero_int<<<1, 1, 0, stream>>>(flag);
    detect_f32<<<1024, 256, 0, stream>>>((const u16*)fp_data, (long)ND * 1024, flag);
    size_t woff = 0;
    auto conv = [&](int idx, long n) {
        float* dst = Wpool + woff; woff += (size_t)n;
        conv_in<<<256, 256, 0, stream>>>(d_in[idx], dst, n, flag);
        return dst;
    };
    float* fp_w1c   = conv(6,  1024L * 512);
    float* fp_w2c   = conv(8,  512L * 256);
    float* gcn_w1c  = conv(10, 64L * 128);
    float* gcn_w2c  = conv(12, 128L * 256);
    float* att_w1c  = conv(14, 256L * 128);
    float* att_b1c  = conv(15, 128);
    float* att_w2c  = conv(16, 128);
    float* rg_w1c   = conv(18, 8L * 256 * 256);
    float* rg_root1c= conv(19, 256L * 256);
    float* rg_w2c   = conv(21, 8L * 256 * 128);
    float* rg_root2c= conv(22, 256L * 128);
    float* lin1_wc  = conv(24, 128L * 64);
    float* lin2_wc  = conv(26, 64L * 2);
    float* lin2_bc  = conv(27, 2);

    auto bn_stats = [&](const float* X, int M, int N) {
        fillf<<<4, 256, 0, stream>>>(stats, 1024, 0.f);
        colstats<<<256, N, 0, stream>>>(X, M, N, stats, stats + 512);
        bn_finalize<<<2, 256, 0, stream>>>(stats, stats + 512, N, M);
    };
    auto batchnorm = [&](float* X, int M, int N, int relu) {
        bn_stats(X, M, N);
        long total = (long)M * N;
        int g = divup(total, 256); if (g > 8192) g = 8192;
        bn_apply<<<g, 256, 0, stream>>>(X, total, N - 1, stats, stats + 512, relu);
    };

    // ---------- fingerprint MLP branch ----------
    gemm64<2, float><<<dim3(64, 8, 1), 256, 0, stream>>>(
        fp_data, 1024, fp_w1c, 512, fp1, 512, ND, 512, 1024, 0, 0, flag, nullptr, nullptr);
    batchnorm(fp1, ND, 512, 1);
    gemm64<0, float><<<dim3(64, 4, 1), 256, 0, stream>>>(
        fp1, 512, fp_w2c, 256, fpb, 256, ND, 256, 512, 0, 0, nullptr, nullptr, nullptr);
    batchnorm(fpb, ND, 256, 1);

    // ---------- molecular GCN branch ----------
    fillf<<<512, 256, 0, stream>>>(dinv, NM, 1.0f);      // self-loop degree
    deg_count<<<2048, 256, 0, stream>>>(mol_dst, EM, dinv);
    rsqrt_inplace<<<512, 256, 0, stream>>>(dinv, NM);

    // layer 1: out width 128, two 64-col chunks -> G1 (bf16)  [fp1 dead]
    for (int c0 = 0; c0 < 128; c0 += 64) {
        gemm64<2, u16><<<dim3(2048, 1, 1), 256, 0, stream>>>(
            mol_x, 64, gcn_w1c + c0, 128, HB, 64, NM, 64, 64, 0, 0, flag, dinv, BIG);
        gcn_edge4<<<8192, 256, 0, stream>>>(HB, dinv, mol_src, mol_dst, EM * 4, BIG);
        bn_stats(BIG, NM, 64);
        bn_chunk_bf16<<<8192, 256, 0, stream>>>(BIG, (long)NM * 64, stats, stats + 512, G1, c0);
    }

    // layer 2: out width 256, four 64-col chunks -> pooled gout
    fillf<<<1024, 256, 0, stream>>>(gout, (long)ND * 256, 0.f);
    fillf<<<16, 256, 0, stream>>>(cntP, ND, 0.f);
    pool_cnt<<<512, 256, 0, stream>>>(mol_batch, NM, cntP);
    for (int c0 = 0; c0 < 256; c0 += 64) {
        gemm64<1, u16><<<dim3(2048, 1, 1), 256, 0, stream>>>(
            G1, 128, gcn_w2c + c0, 256, HB, 64, NM, 64, 128, 0, 0, nullptr, dinv, BIG);
        gcn_edge4<<<8192, 256, 0, stream>>>(HB, dinv, mol_src, mol_dst, EM * 4, BIG);
        bn_stats(BIG, NM, 64);
        bn_apply<<<8192, 256, 0, stream>>>(BIG, (long)NM * 64, 63, stats, stats + 512, 1);
        pool_sum4<<<2048, 256, 0, stream>>>(BIG, mol_batch, (long)NM * 4, gout, c0);
    }
    pool_div<<<1024, 256, 0, stream>>>(gout, cntP, (long)ND * 256, 8);

    // ---------- attention fusion (emb -> xkg rows [0,ND))  [G1 dead] --------
    attention_fuse<<<ND, 128, 0, stream>>>(gout, fpb, att_w1c, att_b1c, att_w2c, xkg, out_beta);
    conv_in<<<512, 256, 0, stream>>>(d_in[17], xkg + (long)ND * 256, (long)NGENE * 256, flag);

    // ---------- RGCN layer 1 (256 -> 256) ----------
    fillf<<<128, 256, 0, stream>>>(cntK, (long)8 * NKG, 0.f);
    kg_cnt<<<2048, 256, 0, stream>>>(kg_dst, kg_et, EK, NKG, cntK);
    gemm64<0, float><<<dim3(divup(NKG, 64), 4, 1), 256, 0, stream>>>(
        xkg, 256, rg_root1c, 256, x2, 256, NKG, 256, 256, 0, 0, nullptr, nullptr, nullptr);
    for (int c0 = 0; c0 < 256; c0 += 64) {
        gemm64<0, float><<<dim3(divup(NKG, 64), 1, 8), 256, 0, stream>>>(
            xkg, 256, rg_w1c + c0, 256, HR, 64, NKG, 64, 256,
            (long)256 * 256, (long)NKG * 64, nullptr, nullptr, nullptr);
        rgcn_edge4<<<4096, 256, 0, stream>>>(HR, kg_src, kg_dst, kg_et, cntK,
                                             EK * 4, NKG, x2, 256, c0);
    }
    batchnorm(x2, NKG, 256, 1);

    // ---------- RGCN layer 2 (256 -> 128) ----------
    gemm64<0, float><<<dim3(divup(NKG, 64), 2, 1), 256, 0, stream>>>(
        x2, 256, rg_root2c, 128, x3, 128, NKG, 128, 256, 0, 0, nullptr, nullptr, nullptr);
    for (int c0 = 0; c0 < 128; c0 += 64) {
        gemm64<0, float><<<dim3(divup(NKG, 64), 1, 8), 256, 0, stream>>>(
            x2, 256, rg_w2c + c0, 128, HR, 64, NKG, 64, 256,
            (long)256 * 128, (long)NKG * 64, nullptr, nullptr, nullptr);
        rgcn_edge4<<<4096, 256, 0, stream>>>(HR, kg_src, kg_dst, kg_et, cntK,
                                             EK * 4, NKG, x3, 128, c0);
    }
    batchnorm(x3, NKG, 128, 1);

    // ---------- classifier head ----------
    gemm64<0, float><<<dim3(divup(NKG, 64), 1, 1), 256, 0, stream>>>(
        x3, 128, lin1_wc, 64, x4, 64, NKG, 64, 128, 0, 0, nullptr, nullptr, nullptr);
    batchnorm(x4, NKG, 64, 1);
    logits_out<<<divup(NKG, 256), 256, 0, stream>>>(x4, lin2_wc, lin2_bc, out_ls, NKG);
}

// Round 7
// 3333.547 us; speedup vs baseline: 8.1523x; 8.1523x over previous
//
#include <hip/hip_runtime.h>
#include <hip/hip_bf16.h>
#include <cstdint>

typedef __hip_bfloat16 bf16;
typedef unsigned short u16;

__device__ __forceinline__ float tofloat(float x){ return x; }
__device__ __forceinline__ float tofloat(bf16 x){ return __bfloat162float(x); }
__device__ __forceinline__ float b2f(u16 a){ return __uint_as_float(((unsigned)a) << 16); }
__device__ __forceinline__ u16 f2b(float f){           // round-to-nearest-even
    unsigned u = __float_as_uint(f);
    return (u16)((u + 0x7FFFu + ((u >> 16) & 1u)) >> 16);
}
__device__ __forceinline__ void store4(float* p, float a, float b, float c, float d){
    *(float4*)p = make_float4(a, b, c, d);
}
__device__ __forceinline__ void store4(u16* p, float a, float b, float c, float d){
    ushort4 v; v.x = f2b(a); v.y = f2b(b); v.z = f2b(c); v.w = f2b(d);
    *(ushort4*)p = v;
}

static inline int divup(long a, long b){ return (int)((a + b - 1) / b); }

// ---------------- input dtype detection -------------------------------------
__global__ void zero_int(int* p){ *p = 0; }

__global__ void detect_f32(const u16* __restrict__ h, long n, int* flag)
{
    long i = (long)blockIdx.x * blockDim.x + threadIdx.x;
    long st = (long)gridDim.x * blockDim.x;
    int c = 0;
    for (; i < n; i += st)
        if (((h[i] >> 7) & 0xFF) == 0xFF) c++;
    if (c) atomicAdd(flag, c);
}

__global__ void conv_in(const void* __restrict__ src, float* __restrict__ dst,
                        long n, const int* __restrict__ flagp)
{
    bool f32 = (*flagp != 0);
    long i = (long)blockIdx.x * blockDim.x + threadIdx.x;
    long st = (long)gridDim.x * blockDim.x;
    for (; i < n; i += st)
        dst[i] = f32 ? ((const float*)src)[i] : tofloat(((const bf16*)src)[i]);
}

// ---------------- 64x64-tile GEMM, 256 thr, 4x4 micro-tile ------------------
// C[M,N] = A[M,K] @ B[K,N].  AM: 0 = A fp32, 1 = A bf16(u16), 2 = dual.
// K multiple of 16 (and of 4 for float4 A loads); N multiple of 4.
template<int AM, typename TC>
__global__ __launch_bounds__(256)
void gemm64(const void* __restrict__ A_, int lda,
            const float* __restrict__ B, int ldb,
            TC* __restrict__ C, int ldc,
            int M, int N, int K, long sB, long sC,
            const int* __restrict__ flagp)
{
    bool af32 = (AM == 0);
    if (AM == 2) af32 = (*flagp != 0);
    const float* Af = (const float*)A_;
    const u16*   Au = (const u16*)A_;
    const float* Bp = B + (long)blockIdx.z * sB;
    TC*          Cp = C + (long)blockIdx.z * sC;

    __shared__ float As[16][68];
    __shared__ float Bs[16][68];

    const int tid = threadIdx.x;
    const int row0 = blockIdx.x * 64, col0 = blockIdx.y * 64;

    float acc[4][4];
#pragma unroll
    for (int i = 0; i < 4; i++)
#pragma unroll
        for (int j = 0; j < 4; j++) acc[i][j] = 0.f;

    const int ar = tid >> 2;            // 0..63 A row
    const int ak = (tid & 3) * 4;       // k offset
    const int bk = tid >> 4;            // 0..15 B k
    const int bc = (tid & 15) * 4;      // col offset
    const int ty4 = (tid >> 4) * 4, tx4 = (tid & 15) * 4;

    for (int k0 = 0; k0 < K; k0 += 16) {
        {
            int row = row0 + ar;
            float x0 = 0.f, x1 = 0.f, x2 = 0.f, x3 = 0.f;
            if (row < M) {
                long base = (long)row * lda + k0 + ak;
                if (af32) {
                    float4 v = *(const float4*)(Af + base);
                    x0 = v.x; x1 = v.y; x2 = v.z; x3 = v.w;
                } else {
                    ushort4 u = *(const ushort4*)(Au + base);
                    x0 = b2f(u.x); x1 = b2f(u.y); x2 = b2f(u.z); x3 = b2f(u.w);
                }
            }
            As[ak + 0][ar] = x0; As[ak + 1][ar] = x1;
            As[ak + 2][ar] = x2; As[ak + 3][ar] = x3;
        }
        {
            int c = col0 + bc;
            float4 v = make_float4(0.f, 0.f, 0.f, 0.f);
            if (c < N) v = *(const float4*)(Bp + (long)(k0 + bk) * ldb + c);
            *(float4*)&Bs[bk][bc] = v;
        }
        __syncthreads();
#pragma unroll
        for (int k = 0; k < 16; k++) {
            float4 a = *(const float4*)&As[k][ty4];
            float4 b = *(const float4*)&Bs[k][tx4];
            acc[0][0] += a.x * b.x; acc[0][1] += a.x * b.y; acc[0][2] += a.x * b.z; acc[0][3] += a.x * b.w;
            acc[1][0] += a.y * b.x; acc[1][1] += a.y * b.y; acc[1][2] += a.y * b.z; acc[1][3] += a.y * b.w;
            acc[2][0] += a.z * b.x; acc[2][1] += a.z * b.y; acc[2][2] += a.z * b.z; acc[2][3] += a.z * b.w;
            acc[3][0] += a.w * b.x; acc[3][1] += a.w * b.y; acc[3][2] += a.w * b.z; acc[3][3] += a.w * b.w;
        }
        __syncthreads();
    }

    int c = col0 + tx4;
#pragma unroll
    for (int i = 0; i < 4; i++) {
        int r = row0 + ty4 + i;
        if (r < M && c < N)
            store4(&Cp[(long)r * ldc + c], acc[i][0], acc[i][1], acc[i][2], acc[i][3]);
    }
}

// ---------------- utility ---------------------------------------------------
__global__ void fillf(float* p, long n, float v)
{
    long i = (long)blockIdx.x * blockDim.x + threadIdx.x;
    long st = (long)gridDim.x * blockDim.x;
    for (; i < n; i += st) p[i] = v;
}

__global__ void filli(int* p, long n, int v)
{
    long i = (long)blockIdx.x * blockDim.x + threadIdx.x;
    long st = (long)gridDim.x * blockDim.x;
    for (; i < n; i += st) p[i] = v;
}

// ---------------- CSR build pieces ------------------------------------------
__global__ void hist_int(const int* __restrict__ key, long n, int* __restrict__ h)
{
    long i = (long)blockIdx.x * blockDim.x + threadIdx.x;
    long st = (long)gridDim.x * blockDim.x;
    for (; i < n; i += st) atomicAdd(&h[key[i]], 1);
}

// exclusive scan of in[0..n) -> out[0..n], single block 1024 threads
__global__ __launch_bounds__(1024)
void scan_excl(const int* __restrict__ in, int* __restrict__ out, int n)
{
    __shared__ int buf[1024];
    __shared__ int carry_s;
    int tid = threadIdx.x;
    if (tid == 0) carry_s = 0;
    __syncthreads();
    for (int base = 0; base < n; base += 4096) {
        int i0 = base + tid * 4;
        int v[4]; int s = 0;
#pragma unroll
        for (int t = 0; t < 4; t++) {
            int idx = i0 + t;
            v[t] = (idx < n) ? in[idx] : 0;
            s += v[t];
        }
        buf[tid] = s;
        __syncthreads();
        for (int off = 1; off < 1024; off <<= 1) {
            int t = (tid >= off) ? buf[tid - off] : 0;
            __syncthreads();
            buf[tid] += t;
            __syncthreads();
        }
        int total = buf[1023];
        int excl = buf[tid] - s + carry_s;
#pragma unroll
        for (int t = 0; t < 4; t++) {
            int idx = i0 + t;
            if (idx < n) out[idx] = excl;
            excl += v[t];
        }
        __syncthreads();
        if (tid == 0) carry_s += total;
        __syncthreads();
    }
    if (tid == 0) out[n] = carry_s;
}

__global__ void bin_by(const int* __restrict__ key, long n,
                       const int* __restrict__ off, int* __restrict__ cursor,
                       int* __restrict__ bins)
{
    long i = (long)blockIdx.x * blockDim.x + threadIdx.x;
    long st = (long)gridDim.x * blockDim.x;
    for (; i < n; i += st) {
        int k = key[i];
        int pos = off[k] + atomicAdd(&cursor[k], 1);
        bins[pos] = (int)i;
    }
}

// dinv[i] = rsqrt(deg[i] + 1)   (self-loop)
__global__ void dinv_from_deg(const int* __restrict__ deg, float* __restrict__ dinv, long n)
{
    long i = (long)blockIdx.x * blockDim.x + threadIdx.x;
    long st = (long)gridDim.x * blockDim.x;
    for (; i < n; i += st) dinv[i] = rsqrtf((float)(deg[i] + 1));
}

// ---------------- batch-norm (per-column, gamma=1 beta=0) -------------------
__global__ void colstats(const float* __restrict__ X, int M, int N,
                         float* __restrict__ s1, float* __restrict__ s2)
{
    int j = threadIdx.x;
    if (j >= N) return;
    int rows = (M + gridDim.x - 1) / gridDim.x;
    int r0 = blockIdx.x * rows;
    int r1 = min(M, r0 + rows);
    float a = 0.f, b = 0.f;
    for (int i = r0; i < r1; i++) {
        float v = X[(long)i * N + j];
        a += v; b += v * v;
    }
    atomicAdd(&s1[j], a);
    atomicAdd(&s2[j], b);
}

__global__ void bn_finalize(float* s1, float* s2, int N, int M)
{
    int j = blockIdx.x * blockDim.x + threadIdx.x;
    if (j >= N) return;
    float mean = s1[j] / (float)M;
    float var  = fmaxf(s2[j] / (float)M - mean * mean, 0.f);
    s1[j] = mean;
    s2[j] = rsqrtf(var + 1e-5f);
}

__global__ void bn_apply(float* X, long total, int mask,
                         const float* __restrict__ s1, const float* __restrict__ s2,
                         int relu)
{
    long i = (long)blockIdx.x * blockDim.x + threadIdx.x;
    long st = (long)gridDim.x * blockDim.x;
    for (; i < total; i += st) {
        int j = (int)(i & mask);
        float y = (X[i] - s1[j]) * s2[j];
        if (relu) y = fmaxf(y, 0.f);
        X[i] = y;
    }
}

// BN+ReLU fp32 chunk [M,64] -> bf16 dst[n*128 + c0 + f]
__global__ void bn_chunk_bf16(const float* __restrict__ X, long total,
                              const float* __restrict__ s1, const float* __restrict__ s2,
                              u16* __restrict__ dst, int c0)
{
    long i = (long)blockIdx.x * blockDim.x + threadIdx.x;
    long st = (long)gridDim.x * blockDim.x;
    for (; i < total; i += st) {
        long n = i >> 6;
        int  f = (int)(i & 63);
        float y = fmaxf((X[i] - s1[f]) * s2[f], 0.f);
        dst[n * 128 + c0 + f] = f2b(y);
    }
}

// ---------------- CSR aggregation kernels (no atomics) ----------------------
// mol GCN: out[d,lane] = h[d,lane]*dinv[d]^2 + sum_edges h[s,lane]*dinv[s]*dinv[d]
__global__ __launch_bounds__(256)
void mol_aggregate(const u16* __restrict__ hb, const float* __restrict__ dinv,
                   const int* __restrict__ off, const int* __restrict__ bins,
                   const int* __restrict__ src, int NM, float* __restrict__ out)
{
    int wid  = (int)(((long)blockIdx.x * 256 + threadIdx.x) >> 6);
    int lane = threadIdx.x & 63;
    if (wid >= NM) return;
    float dv = dinv[wid];
    float acc = b2f(hb[(long)wid * 64 + lane]) * dv * dv;
    int j1 = off[wid + 1];
    for (int j = off[wid]; j < j1; j++) {
        int e = bins[j];
        int s = src[e];
        acc += b2f(hb[(long)s * 64 + lane]) * (dinv[s] * dv);
    }
    out[(long)wid * 64 + lane] = acc;
}

// RGCN: out[d, c0+lane] += sum_edges hr[r,s,lane] / max(cnt[r,d],1)
__global__ __launch_bounds__(256)
void rgcn_aggregate(const float* __restrict__ hr, const int* __restrict__ off,
                    const int* __restrict__ bins, const int* __restrict__ src,
                    const int* __restrict__ et, const float* __restrict__ cnt,
                    int NKG, float* __restrict__ out, int ldout, int c0)
{
    int wid  = (int)(((long)blockIdx.x * 256 + threadIdx.x) >> 6);
    int lane = threadIdx.x & 63;
    if (wid >= NKG) return;
    float acc = 0.f;
    int j1 = off[wid + 1];
    for (int j = off[wid]; j < j1; j++) {
        int e = bins[j];
        int r = et[e], s = src[e];
        float nrm = 1.0f / fmaxf(cnt[(long)r * NKG + wid], 1.0f);
        acc += hr[((long)r * NKG + s) * 64 + lane] * nrm;
    }
    long o = (long)wid * ldout + c0 + lane;
    out[o] += acc;
}

// mean-pool: gout[b, c0+lane] = mean over nodes of BIG[n,lane]
__global__ __launch_bounds__(256)
void pool_aggregate(const float* __restrict__ g, const int* __restrict__ off,
                    const int* __restrict__ bins, int ND, float* __restrict__ gout, int c0)
{
    int wid  = (int)(((long)blockIdx.x * 256 + threadIdx.x) >> 6);
    int lane = threadIdx.x & 63;
    if (wid >= ND) return;
    int j0 = off[wid], j1 = off[wid + 1];
    float acc = 0.f;
    for (int j = j0; j < j1; j++)
        acc += g[(long)bins[j] * 64 + lane];
    float c = fmaxf((float)(j1 - j0), 1.0f);
    gout[(long)wid * 256 + c0 + lane] = acc / c;
}

// ---------------- (r,d) count histogram for RGCN mean -----------------------
__global__ void kg_cnt(const int* __restrict__ dst, const int* __restrict__ et,
                       long E, int NKG, float* cnt)
{
    long i = (long)blockIdx.x * blockDim.x + threadIdx.x;
    long st = (long)gridDim.x * blockDim.x;
    for (; i < E; i += st) atomicAdd(&cnt[(long)et[i] * NKG + dst[i]], 1.0f);
}

// ---------------- attention fusion (one 128-thread block per drug) ----------
__global__ void attention_fuse(const float* __restrict__ go, const float* __restrict__ fpv,
                               const float* __restrict__ W1, const float* __restrict__ B1,
                               const float* __restrict__ W2,
                               float* __restrict__ emb, float* __restrict__ beta_out)
{
    int d = blockIdx.x;
    int t = threadIdx.x;
    __shared__ float z[2][256];
    __shared__ float red[128];
    for (int c = t; c < 256; c += 128) {
        z[0][c] = go[(long)d * 256 + c];
        z[1][c] = fpv[(long)d * 256 + c];
    }
    __syncthreads();
    float s[2];
    for (int v = 0; v < 2; v++) {
        float acc = B1[t];
        for (int k = 0; k < 256; k++) acc += z[v][k] * W1[k * 128 + t];
        red[t] = tanhf(acc) * W2[t];
        __syncthreads();
        for (int off = 64; off > 0; off >>= 1) {
            if (t < off) red[t] += red[t + off];
            __syncthreads();
        }
        s[v] = red[0];
        __syncthreads();
    }
    float m = fmaxf(s[0], s[1]);
    float e0 = expf(s[0] - m), e1 = expf(s[1] - m);
    float inv = 1.0f / (e0 + e1);
    float b0 = e0 * inv, b1 = e1 * inv;
    for (int c = t; c < 256; c += 128)
        emb[(long)d * 256 + c] = b0 * z[0][c] + b1 * z[1][c];
    if (t == 0) {
        beta_out[d * 2 + 0] = b0;
        beta_out[d * 2 + 1] = b1;
    }
}

// ---------------- final linear + log_softmax (fp32 out) ---------------------
__global__ void logits_out(const float* __restrict__ x4, const float* __restrict__ w,
                           const float* __restrict__ b, float* __restrict__ out, int NKG)
{
    int i = blockIdx.x * blockDim.x + threadIdx.x;
    if (i >= NKG) return;
    float a0 = b[0], a1 = b[1];
    for (int k = 0; k < 64; k++) {
        float v = x4[(long)i * 64 + k];
        a0 += v * w[k * 2 + 0];
        a1 += v * w[k * 2 + 1];
    }
    float m = fmaxf(a0, a1);
    float lse = m + logf(expf(a0 - m) + expf(a1 - m));
    out[i * 2 + 0] = a0 - lse;
    out[i * 2 + 1] = a1 - lse;
}

// ============================================================================
extern "C" void kernel_launch(void* const* d_in, const int* in_sizes, int n_in,
                              void* d_out, int out_size, void* d_ws, size_t ws_size,
                              hipStream_t stream)
{
    (void)in_sizes; (void)n_in; (void)out_size; (void)ws_size;
    const int ND = 4096, NM = 131072, NKG = 9510, NGENE = 5414;
    const long EM = 524288, EK = 524288;

    const void* fp_data = d_in[0];
    const void* mol_x   = d_in[1];
    const int*  mol_batch = (const int*)d_in[2];
    const int*  mol_ei  = (const int*)d_in[3];
    const int*  kg_ei   = (const int*)d_in[4];
    const int*  kg_et   = (const int*)d_in[5];

    const int* mol_src = mol_ei;
    const int* mol_dst = mol_ei + EM;
    const int* kg_src  = kg_ei;
    const int* kg_dst  = kg_ei + EK;

    float* out_ls   = (float*)d_out;          // [9510,2] fp32
    float* out_beta = (float*)d_out + 19020;  // [4096,2,1] fp32

    // ---- workspace carve (~107 MB) ----
    char* wp = (char*)d_ws;
    auto carve = [&](size_t bytes) { char* p = wp; wp += (bytes + 255) & ~(size_t)255; return p; };
    float* stats = (float*)carve(4096);
    int*   flag  = (int*)carve(256);
    float* dinv  = (float*)carve((size_t)NM * 4);
    float* cntK  = (float*)carve((size_t)8 * NKG * 4);
    float* Wpool = (float*)carve((size_t)1630000 * 4);     // 6.5 MB fp32 weights
    float* fpb   = (float*)carve((size_t)ND * 256 * 4);
    float* gout  = (float*)carve((size_t)ND * 256 * 4);
    // CSR arrays
    int* mdeg = (int*)carve((size_t)NM * 4);
    int* moff = (int*)carve((size_t)(NM + 1) * 4);
    int* mcur = (int*)carve((size_t)NM * 4);
    int* mbins= (int*)carve((size_t)EM * 4);
    int* kdeg = (int*)carve((size_t)NKG * 4);
    int* koff = (int*)carve((size_t)(NKG + 1) * 4);
    int* kcur = (int*)carve((size_t)NKG * 4);
    int* kbins= (int*)carve((size_t)EK * 4);
    int* pdeg = (int*)carve((size_t)ND * 4);
    int* poff = (int*)carve((size_t)(ND + 1) * 4);
    int* pcur = (int*)carve((size_t)ND * 4);
    int* pbins= (int*)carve((size_t)NM * 4);
    // big regions (time-shared)
    char*  REG1  = carve((size_t)NM * 128 * 2);            // 33.6 MB: fp1 / G1(bf16) / xkg..x4
    char*  REG2  = carve((size_t)NM * 64 * 4);             // 33.6 MB: BIG / HR
    u16*   HB    = (u16*)carve((size_t)NM * 64 * 2);       // 16.8 MB bf16 h chunk

    float* fp1 = (float*)REG1;
    u16*   G1  = (u16*)REG1;
    float* xkg = (float*)REG1;
    float* x2  = xkg + (size_t)NKG * 256;
    float* x3  = x2  + (size_t)NKG * 256;
    float* x4  = x3  + (size_t)NKG * 128;
    float* BIG = (float*)REG2;                 // [NM,64] fp32
    float* HR  = (float*)REG2;                 // [8,NKG,64] fp32

    // ---- dtype detection + parameter conversion ----
    zero_int<<<1, 1, 0, stream>>>(flag);
    detect_f32<<<1024, 256, 0, stream>>>((const u16*)fp_data, (long)ND * 1024, flag);
    size_t woff = 0;
    auto conv = [&](int idx, long n) {
        float* dst = Wpool + woff; woff += (size_t)n;
        conv_in<<<256, 256, 0, stream>>>(d_in[idx], dst, n, flag);
        return dst;
    };
    float* fp_w1c   = conv(6,  1024L * 512);
    float* fp_w2c   = conv(8,  512L * 256);
    float* gcn_w1c  = conv(10, 64L * 128);
    float* gcn_w2c  = conv(12, 128L * 256);
    float* att_w1c  = conv(14, 256L * 128);
    float* att_b1c  = conv(15, 128);
    float* att_w2c  = conv(16, 128);
    float* rg_w1c   = conv(18, 8L * 256 * 256);
    float* rg_root1c= conv(19, 256L * 256);
    float* rg_w2c   = conv(21, 8L * 256 * 128);
    float* rg_root2c= conv(22, 256L * 128);
    float* lin1_wc  = conv(24, 128L * 64);
    float* lin2_wc  = conv(26, 64L * 2);
    float* lin2_bc  = conv(27, 2);

    // ---- CSR builds ----
    filli<<<512, 256, 0, stream>>>(mdeg, NM, 0);
    hist_int<<<2048, 256, 0, stream>>>(mol_dst, EM, mdeg);
    scan_excl<<<1, 1024, 0, stream>>>(mdeg, moff, NM);
    filli<<<512, 256, 0, stream>>>(mcur, NM, 0);
    bin_by<<<2048, 256, 0, stream>>>(mol_dst, EM, moff, mcur, mbins);
    dinv_from_deg<<<512, 256, 0, stream>>>(mdeg, dinv, NM);

    filli<<<64, 256, 0, stream>>>(kdeg, NKG, 0);
    hist_int<<<2048, 256, 0, stream>>>(kg_dst, EK, kdeg);
    scan_excl<<<1, 1024, 0, stream>>>(kdeg, koff, NKG);
    filli<<<64, 256, 0, stream>>>(kcur, NKG, 0);
    bin_by<<<2048, 256, 0, stream>>>(kg_dst, EK, koff, kcur, kbins);
    fillf<<<128, 256, 0, stream>>>(cntK, (long)8 * NKG, 0.f);
    kg_cnt<<<2048, 256, 0, stream>>>(kg_dst, kg_et, EK, NKG, cntK);

    filli<<<16, 256, 0, stream>>>(pdeg, ND, 0);
    hist_int<<<512, 256, 0, stream>>>(mol_batch, NM, pdeg);
    scan_excl<<<1, 1024, 0, stream>>>(pdeg, poff, ND);
    filli<<<16, 256, 0, stream>>>(pcur, ND, 0);
    bin_by<<<512, 256, 0, stream>>>(mol_batch, NM, poff, pcur, pbins);

    auto bn_stats = [&](const float* X, int M, int N) {
        fillf<<<4, 256, 0, stream>>>(stats, 1024, 0.f);
        colstats<<<256, N, 0, stream>>>(X, M, N, stats, stats + 512);
        bn_finalize<<<2, 256, 0, stream>>>(stats, stats + 512, N, M);
    };
    auto batchnorm = [&](float* X, int M, int N, int relu) {
        bn_stats(X, M, N);
        long total = (long)M * N;
        int g = divup(total, 256); if (g > 8192) g = 8192;
        bn_apply<<<g, 256, 0, stream>>>(X, total, N - 1, stats, stats + 512, relu);
    };

    // ---------- fingerprint MLP branch ----------
    gemm64<2, float><<<dim3(64, 8, 1), 256, 0, stream>>>(
        fp_data, 1024, fp_w1c, 512, fp1, 512, ND, 512, 1024, 0, 0, flag);
    batchnorm(fp1, ND, 512, 1);
    gemm64<0, float><<<dim3(64, 4, 1), 256, 0, stream>>>(
        fp1, 512, fp_w2c, 256, fpb, 256, ND, 256, 512, 0, 0, nullptr);
    batchnorm(fpb, ND, 256, 1);

    // ---------- molecular GCN layer 1 (64 -> 128), two 64-col chunks --------
    for (int c0 = 0; c0 < 128; c0 += 64) {
        gemm64<2, u16><<<dim3(2048, 1, 1), 256, 0, stream>>>(
            mol_x, 64, gcn_w1c + c0, 128, HB, 64, NM, 64, 64, 0, 0, flag);
        mol_aggregate<<<32768, 256, 0, stream>>>(HB, dinv, moff, mbins, mol_src, NM, BIG);
        bn_stats(BIG, NM, 64);
        bn_chunk_bf16<<<8192, 256, 0, stream>>>(BIG, (long)NM * 64, stats, stats + 512, G1, c0);
    }

    // ---------- molecular GCN layer 2 (128 -> 256) + mean pool --------------
    for (int c0 = 0; c0 < 256; c0 += 64) {
        gemm64<1, u16><<<dim3(2048, 1, 1), 256, 0, stream>>>(
            G1, 128, gcn_w2c + c0, 256, HB, 64, NM, 64, 128, 0, 0, nullptr);
        mol_aggregate<<<32768, 256, 0, stream>>>(HB, dinv, moff, mbins, mol_src, NM, BIG);
        bn_stats(BIG, NM, 64);
        bn_apply<<<8192, 256, 0, stream>>>(BIG, (long)NM * 64, 63, stats, stats + 512, 1);
        pool_aggregate<<<1024, 256, 0, stream>>>(BIG, poff, pbins, ND, gout, c0);
    }

    // ---------- attention fusion (emb -> xkg rows [0,ND))  [G1 dead] --------
    attention_fuse<<<ND, 128, 0, stream>>>(gout, fpb, att_w1c, att_b1c, att_w2c, xkg, out_beta);
    conv_in<<<512, 256, 0, stream>>>(d_in[17], xkg + (long)ND * 256, (long)NGENE * 256, flag);

    // ---------- RGCN layer 1 (256 -> 256) ----------
    gemm64<0, float><<<dim3(divup(NKG, 64), 4, 1), 256, 0, stream>>>(
        xkg, 256, rg_root1c, 256, x2, 256, NKG, 256, 256, 0, 0, nullptr);
    for (int c0 = 0; c0 < 256; c0 += 64) {
        gemm64<0, float><<<dim3(divup(NKG, 64), 1, 8), 256, 0, stream>>>(
            xkg, 256, rg_w1c + c0, 256, HR, 64, NKG, 64, 256,
            (long)256 * 256, (long)NKG * 64, nullptr);
        rgcn_aggregate<<<2378, 256, 0, stream>>>(HR, koff, kbins, kg_src, kg_et, cntK,
                                                 NKG, x2, 256, c0);
    }
    batchnorm(x2, NKG, 256, 1);

    // ---------- RGCN layer 2 (256 -> 128) ----------
    gemm64<0, float><<<dim3(divup(NKG, 64), 2, 1), 256, 0, stream>>>(
        x2, 256, rg_root2c, 128, x3, 128, NKG, 128, 256, 0, 0, nullptr);
    for (int c0 = 0; c0 < 128; c0 += 64) {
        gemm64<0, float><<<dim3(divup(NKG, 64), 1, 8), 256, 0, stream>>>(
            x2, 256, rg_w2c + c0, 128, HR, 64, NKG, 64, 256,
            (long)256 * 128, (long)NKG * 64, nullptr);
        rgcn_aggregate<<<2378, 256, 0, stream>>>(HR, koff, kbins, kg_src, kg_et, cntK,
                                                 NKG, x3, 128, c0);
    }
    batchnorm(x3, NKG, 128, 1);

    // ---------- classifier head ----------
    gemm64<0, float><<<dim3(divup(NKG, 64), 1, 1), 256, 0, stream>>>(
        x3, 128, lin1_wc, 64, x4, 64, NKG, 64, 128, 0, 0, nullptr);
    batchnorm(x4, NKG, 64, 1);
    logits_out<<<divup(NKG, 256), 256, 0, stream>>>(x4, lin2_wc, lin2_bc, out_ls, NKG);
}

// Round 8
// 2863.500 us; speedup vs baseline: 9.4905x; 1.1642x over previous
//
#include <hip/hip_runtime.h>
#include <hip/hip_bf16.h>
#include <cstdint>

typedef __hip_bfloat16 bf16;
typedef unsigned short u16;

__device__ __forceinline__ float tofloat(float x){ return x; }
__device__ __forceinline__ float tofloat(bf16 x){ return __bfloat162float(x); }
__device__ __forceinline__ float b2f(u16 a){ return __uint_as_float(((unsigned)a) << 16); }
__device__ __forceinline__ u16 f2b(float f){           // round-to-nearest-even
    unsigned u = __float_as_uint(f);
    return (u16)((u + 0x7FFFu + ((u >> 16) & 1u)) >> 16);
}
__device__ __forceinline__ void store4(float* p, float a, float b, float c, float d){
    *(float4*)p = make_float4(a, b, c, d);
}
__device__ __forceinline__ void store4(u16* p, float a, float b, float c, float d){
    ushort4 v; v.x = f2b(a); v.y = f2b(b); v.z = f2b(c); v.w = f2b(d);
    *(ushort4*)p = v;
}

static inline int divup(long a, long b){ return (int)((a + b - 1) / b); }

// ---------------- input dtype detection -------------------------------------
__global__ void zero_int(int* p){ *p = 0; }

__global__ void detect_f32(const u16* __restrict__ h, long n, int* flag)
{
    long i = (long)blockIdx.x * blockDim.x + threadIdx.x;
    long st = (long)gridDim.x * blockDim.x;
    int c = 0;
    for (; i < n; i += st)
        if (((h[i] >> 7) & 0xFF) == 0xFF) c++;
    if (c) atomicAdd(flag, c);
}

__global__ void conv_in(const void* __restrict__ src, float* __restrict__ dst,
                        long n, const int* __restrict__ flagp)
{
    bool f32 = (*flagp != 0);
    long i = (long)blockIdx.x * blockDim.x + threadIdx.x;
    long st = (long)gridDim.x * blockDim.x;
    for (; i < n; i += st)
        dst[i] = f32 ? ((const float*)src)[i] : tofloat(((const bf16*)src)[i]);
}

// ---------------- 64x64-tile GEMM, 256 thr, 4x4 micro-tile ------------------
template<int AM, typename TC>
__global__ __launch_bounds__(256)
void gemm64(const void* __restrict__ A_, int lda,
            const float* __restrict__ B, int ldb,
            TC* __restrict__ C, int ldc,
            int M, int N, int K, long sB, long sC,
            const int* __restrict__ flagp)
{
    bool af32 = (AM == 0);
    if (AM == 2) af32 = (*flagp != 0);
    const float* Af = (const float*)A_;
    const u16*   Au = (const u16*)A_;
    const float* Bp = B + (long)blockIdx.z * sB;
    TC*          Cp = C + (long)blockIdx.z * sC;

    __shared__ float As[16][68];
    __shared__ float Bs[16][68];

    const int tid = threadIdx.x;
    const int row0 = blockIdx.x * 64, col0 = blockIdx.y * 64;

    float acc[4][4];
#pragma unroll
    for (int i = 0; i < 4; i++)
#pragma unroll
        for (int j = 0; j < 4; j++) acc[i][j] = 0.f;

    const int ar = tid >> 2;
    const int ak = (tid & 3) * 4;
    const int bk = tid >> 4;
    const int bc = (tid & 15) * 4;
    const int ty4 = (tid >> 4) * 4, tx4 = (tid & 15) * 4;

    for (int k0 = 0; k0 < K; k0 += 16) {
        {
            int row = row0 + ar;
            float x0 = 0.f, x1 = 0.f, x2 = 0.f, x3 = 0.f;
            if (row < M) {
                long base = (long)row * lda + k0 + ak;
                if (af32) {
                    float4 v = *(const float4*)(Af + base);
                    x0 = v.x; x1 = v.y; x2 = v.z; x3 = v.w;
                } else {
                    ushort4 u = *(const ushort4*)(Au + base);
                    x0 = b2f(u.x); x1 = b2f(u.y); x2 = b2f(u.z); x3 = b2f(u.w);
                }
            }
            As[ak + 0][ar] = x0; As[ak + 1][ar] = x1;
            As[ak + 2][ar] = x2; As[ak + 3][ar] = x3;
        }
        {
            int c = col0 + bc;
            float4 v = make_float4(0.f, 0.f, 0.f, 0.f);
            if (c < N) v = *(const float4*)(Bp + (long)(k0 + bk) * ldb + c);
            *(float4*)&Bs[bk][bc] = v;
        }
        __syncthreads();
#pragma unroll
        for (int k = 0; k < 16; k++) {
            float4 a = *(const float4*)&As[k][ty4];
            float4 b = *(const float4*)&Bs[k][tx4];
            acc[0][0] += a.x * b.x; acc[0][1] += a.x * b.y; acc[0][2] += a.x * b.z; acc[0][3] += a.x * b.w;
            acc[1][0] += a.y * b.x; acc[1][1] += a.y * b.y; acc[1][2] += a.y * b.z; acc[1][3] += a.y * b.w;
            acc[2][0] += a.z * b.x; acc[2][1] += a.z * b.y; acc[2][2] += a.z * b.z; acc[2][3] += a.z * b.w;
            acc[3][0] += a.w * b.x; acc[3][1] += a.w * b.y; acc[3][2] += a.w * b.z; acc[3][3] += a.w * b.w;
        }
        __syncthreads();
    }

    int c = col0 + tx4;
#pragma unroll
    for (int i = 0; i < 4; i++) {
        int r = row0 + ty4 + i;
        if (r < M && c < N)
            store4(&Cp[(long)r * ldc + c], acc[i][0], acc[i][1], acc[i][2], acc[i][3]);
    }
}

// ---------------- utility ---------------------------------------------------
__global__ void filli(int* p, long n, int v)
{
    long i = (long)blockIdx.x * blockDim.x + threadIdx.x;
    long st = (long)gridDim.x * blockDim.x;
    for (; i < n; i += st) p[i] = v;
}

__global__ void fillf(float* p, long n, float v)
{
    long i = (long)blockIdx.x * blockDim.x + threadIdx.x;
    long st = (long)gridDim.x * blockDim.x;
    for (; i < n; i += st) p[i] = v;
}

// ---------------- CSR build pieces ------------------------------------------
__global__ void hist_int(const int* __restrict__ key, long n, int* __restrict__ h)
{
    long i = (long)blockIdx.x * blockDim.x + threadIdx.x;
    long st = (long)gridDim.x * blockDim.x;
    for (; i < n; i += st) atomicAdd(&h[key[i]], 1);
}

// 3-kernel exclusive scan: block sums -> tiny serial scan -> local scan+carry
__global__ __launch_bounds__(1024)
void scan_bsum(const int* __restrict__ in, int n, int* __restrict__ btot)
{
    __shared__ int sh[1024];
    int tid = threadIdx.x;
    int i0 = blockIdx.x * 4096 + tid * 4;
    int s = 0;
#pragma unroll
    for (int t = 0; t < 4; t++) { int idx = i0 + t; s += (idx < n) ? in[idx] : 0; }
    sh[tid] = s;
    __syncthreads();
    for (int off = 512; off > 0; off >>= 1) {
        if (tid < off) sh[tid] += sh[tid + off];
        __syncthreads();
    }
    if (tid == 0) btot[blockIdx.x] = sh[0];
}

__global__ void scan_tiny(const int* __restrict__ btot, int nb, int* __restrict__ boff)
{
    if (threadIdx.x == 0) {
        int c = 0;
        for (int b = 0; b < nb; b++) { boff[b] = c; c += btot[b]; }
        boff[nb] = c;
    }
}

__global__ __launch_bounds__(1024)
void scan_final(const int* __restrict__ in, int n, const int* __restrict__ boff,
                int nb, int* __restrict__ out)
{
    __shared__ int buf[1024];
    int tid = threadIdx.x;
    int base = blockIdx.x * 4096;
    int i0 = base + tid * 4;
    int v[4]; int s = 0;
#pragma unroll
    for (int t = 0; t < 4; t++) {
        int idx = i0 + t;
        v[t] = (idx < n) ? in[idx] : 0;
        s += v[t];
    }
    buf[tid] = s;
    __syncthreads();
    for (int off = 1; off < 1024; off <<= 1) {
        int t = (tid >= off) ? buf[tid - off] : 0;
        __syncthreads();
        buf[tid] += t;
        __syncthreads();
    }
    int excl = buf[tid] - s + boff[blockIdx.x];
#pragma unroll
    for (int t = 0; t < 4; t++) {
        int idx = i0 + t;
        if (idx < n) out[idx] = excl;
        excl += v[t];
    }
    if (blockIdx.x == 0 && tid == 0) out[n] = boff[nb];
}

__global__ void bin_by(const int* __restrict__ key, long n,
                       const int* __restrict__ off, int* __restrict__ cursor,
                       int* __restrict__ bins)
{
    long i = (long)blockIdx.x * blockDim.x + threadIdx.x;
    long st = (long)gridDim.x * blockDim.x;
    for (; i < n; i += st) {
        int k = key[i];
        int pos = off[k] + atomicAdd(&cursor[k], 1);
        bins[pos] = (int)i;
    }
}

__global__ void dinv_from_deg(const int* __restrict__ deg, float* __restrict__ dinv, long n)
{
    long i = (long)blockIdx.x * blockDim.x + threadIdx.x;
    long st = (long)gridDim.x * blockDim.x;
    for (; i < n; i += st) dinv[i] = rsqrtf((float)(deg[i] + 1));
}

// ---------------- batch-norm: 2-pass atomic-free column stats ---------------
// pass 1: blockDim = N*G (G row-groups). partials p1/p2 [gridDim][N].
__global__ __launch_bounds__(512)
void colstats_part(const float* __restrict__ X, int M, int N, int lgN, int G,
                   float* __restrict__ p1, float* __restrict__ p2)
{
    __shared__ float sh1[512], sh2[512];
    int tid = threadIdx.x;
    int col = tid & (N - 1);
    int grp = tid >> lgN;
    float s1 = 0.f, s2 = 0.f;
    for (long row = (long)blockIdx.x * G + grp; row < M; row += (long)gridDim.x * G) {
        float v = X[row * N + col];
        s1 += v; s2 += v * v;
    }
    sh1[tid] = s1; sh2[tid] = s2;
    __syncthreads();
    if (grp == 0) {
        for (int g = 1; g < G; g++) { s1 += sh1[col + (g << lgN)]; s2 += sh2[col + (g << lgN)]; }
        p1[blockIdx.x * N + col] = s1;
        p2[blockIdx.x * N + col] = s2;
    }
}

// pass 2: N threads; absorbs bn_finalize. stats: s1=mean, s2=rstd.
__global__ void colstats_reduce(const float* __restrict__ p1, const float* __restrict__ p2,
                                int nblk, int N, float invM,
                                float* __restrict__ s1o, float* __restrict__ s2o)
{
    int j = threadIdx.x;
    if (j >= N) return;
    float a = 0.f, c = 0.f;
    for (int b = 0; b < nblk; b += 4) {
        a += p1[(b + 0) * N + j] + p1[(b + 1) * N + j] + p1[(b + 2) * N + j] + p1[(b + 3) * N + j];
        c += p2[(b + 0) * N + j] + p2[(b + 1) * N + j] + p2[(b + 2) * N + j] + p2[(b + 3) * N + j];
    }
    float mean = a * invM;
    float var  = fmaxf(c * invM - mean * mean, 0.f);
    s1o[j] = mean;
    s2o[j] = rsqrtf(var + 1e-5f);
}

__global__ void bn_apply(float* X, long total, int mask,
                         const float* __restrict__ s1, const float* __restrict__ s2,
                         int relu)
{
    long i = (long)blockIdx.x * blockDim.x + threadIdx.x;
    long st = (long)gridDim.x * blockDim.x;
    for (; i < total; i += st) {
        int j = (int)(i & mask);
        float y = (X[i] - s1[j]) * s2[j];
        if (relu) y = fmaxf(y, 0.f);
        X[i] = y;
    }
}

// BN+ReLU fp32 chunk [M,64] -> bf16 dst[n*128 + c0 + f]
__global__ void bn_chunk_bf16(const float* __restrict__ X, long total,
                              const float* __restrict__ s1, const float* __restrict__ s2,
                              u16* __restrict__ dst, int c0)
{
    long i = (long)blockIdx.x * blockDim.x + threadIdx.x;
    long st = (long)gridDim.x * blockDim.x;
    for (; i < total; i += st) {
        long n = i >> 6;
        int  f = (int)(i & 63);
        float y = fmaxf((X[i] - s1[f]) * s2[f], 0.f);
        dst[n * 128 + c0 + f] = f2b(y);
    }
}

// ---------------- CSR aggregation kernels (no atomics) ----------------------
__global__ __launch_bounds__(256)
void mol_aggregate(const u16* __restrict__ hb, const float* __restrict__ dinv,
                   const int* __restrict__ off, const int* __restrict__ bins,
                   const int* __restrict__ src, int NM, float* __restrict__ out)
{
    int wid  = (int)(((long)blockIdx.x * 256 + threadIdx.x) >> 6);
    int lane = threadIdx.x & 63;
    if (wid >= NM) return;
    float dv = dinv[wid];
    float acc = b2f(hb[(long)wid * 64 + lane]) * dv * dv;
    int j1 = off[wid + 1];
    for (int j = off[wid]; j < j1; j++) {
        int e = bins[j];
        int s = src[e];
        acc += b2f(hb[(long)s * 64 + lane]) * (dinv[s] * dv);
    }
    out[(long)wid * 64 + lane] = acc;
}

__global__ __launch_bounds__(256)
void rgcn_aggregate(const float* __restrict__ hr, const int* __restrict__ off,
                    const int* __restrict__ bins, const int* __restrict__ src,
                    const int* __restrict__ et, const float* __restrict__ cnt,
                    int NKG, float* __restrict__ out, int ldout, int c0)
{
    int wid  = (int)(((long)blockIdx.x * 256 + threadIdx.x) >> 6);
    int lane = threadIdx.x & 63;
    if (wid >= NKG) return;
    float acc = 0.f;
    int j1 = off[wid + 1];
    for (int j = off[wid]; j < j1; j++) {
        int e = bins[j];
        int r = et[e], s = src[e];
        float nrm = 1.0f / fmaxf(cnt[(long)r * NKG + wid], 1.0f);
        acc += hr[((long)r * NKG + s) * 64 + lane] * nrm;
    }
    long o = (long)wid * ldout + c0 + lane;
    out[o] += acc;
}

// mean-pool with fused BN+ReLU of the source chunk
__global__ __launch_bounds__(256)
void pool_aggregate_bn(const float* __restrict__ g, const int* __restrict__ off,
                       const int* __restrict__ bins, int ND,
                       const float* __restrict__ s1, const float* __restrict__ s2,
                       float* __restrict__ gout, int c0)
{
    int wid  = (int)(((long)blockIdx.x * 256 + threadIdx.x) >> 6);
    int lane = threadIdx.x & 63;
    if (wid >= ND) return;
    float m = s1[lane], r = s2[lane];
    int j0 = off[wid], j1 = off[wid + 1];
    float acc = 0.f;
    for (int j = j0; j < j1; j++)
        acc += fmaxf((g[(long)bins[j] * 64 + lane] - m) * r, 0.f);
    float c = fmaxf((float)(j1 - j0), 1.0f);
    gout[(long)wid * 256 + c0 + lane] = acc / c;
}

// ---------------- (r,d) count histogram for RGCN mean -----------------------
__global__ void kg_cnt(const int* __restrict__ dst, const int* __restrict__ et,
                       long E, int NKG, float* cnt)
{
    long i = (long)blockIdx.x * blockDim.x + threadIdx.x;
    long st = (long)gridDim.x * blockDim.x;
    for (; i < E; i += st) atomicAdd(&cnt[(long)et[i] * NKG + dst[i]], 1.0f);
}

// ---------------- attention fusion (one 128-thread block per drug) ----------
__global__ void attention_fuse(const float* __restrict__ go, const float* __restrict__ fpv,
                               const float* __restrict__ W1, const float* __restrict__ B1,
                               const float* __restrict__ W2,
                               float* __restrict__ emb, float* __restrict__ beta_out)
{
    int d = blockIdx.x;
    int t = threadIdx.x;
    __shared__ float z[2][256];
    __shared__ float red[128];
    for (int c = t; c < 256; c += 128) {
        z[0][c] = go[(long)d * 256 + c];
        z[1][c] = fpv[(long)d * 256 + c];
    }
    __syncthreads();
    float s[2];
    for (int v = 0; v < 2; v++) {
        float acc = B1[t];
        for (int k = 0; k < 256; k++) acc += z[v][k] * W1[k * 128 + t];
        red[t] = tanhf(acc) * W2[t];
        __syncthreads();
        for (int off = 64; off > 0; off >>= 1) {
            if (t < off) red[t] += red[t + off];
            __syncthreads();
        }
        s[v] = red[0];
        __syncthreads();
    }
    float m = fmaxf(s[0], s[1]);
    float e0 = expf(s[0] - m), e1 = expf(s[1] - m);
    float inv = 1.0f / (e0 + e1);
    float b0 = e0 * inv, b1 = e1 * inv;
    for (int c = t; c < 256; c += 128)
        emb[(long)d * 256 + c] = b0 * z[0][c] + b1 * z[1][c];
    if (t == 0) {
        beta_out[d * 2 + 0] = b0;
        beta_out[d * 2 + 1] = b1;
    }
}

// ---------------- final linear + log_softmax, fused BN on x4 ----------------
__global__ void logits_out_bn(const float* __restrict__ x4,
                              const float* __restrict__ s1, const float* __restrict__ s2,
                              const float* __restrict__ w, const float* __restrict__ b,
                              float* __restrict__ out, int NKG)
{
    int i = blockIdx.x * blockDim.x + threadIdx.x;
    if (i >= NKG) return;
    float a0 = b[0], a1 = b[1];
    for (int k = 0; k < 64; k++) {
        float v = fmaxf((x4[(long)i * 64 + k] - s1[k]) * s2[k], 0.f);
        a0 += v * w[k * 2 + 0];
        a1 += v * w[k * 2 + 1];
    }
    float m = fmaxf(a0, a1);
    float lse = m + logf(expf(a0 - m) + expf(a1 - m));
    out[i * 2 + 0] = a0 - lse;
    out[i * 2 + 1] = a1 - lse;
}

// ============================================================================
extern "C" void kernel_launch(void* const* d_in, const int* in_sizes, int n_in,
                              void* d_out, int out_size, void* d_ws, size_t ws_size,
                              hipStream_t stream)
{
    (void)in_sizes; (void)n_in; (void)out_size; (void)ws_size;
    const int ND = 4096, NM = 131072, NKG = 9510, NGENE = 5414;
    const long EM = 524288, EK = 524288;

    const void* fp_data = d_in[0];
    const void* mol_x   = d_in[1];
    const int*  mol_batch = (const int*)d_in[2];
    const int*  mol_ei  = (const int*)d_in[3];
    const int*  kg_ei   = (const int*)d_in[4];
    const int*  kg_et   = (const int*)d_in[5];

    const int* mol_src = mol_ei;
    const int* mol_dst = mol_ei + EM;
    const int* kg_src  = kg_ei;
    const int* kg_dst  = kg_ei + EK;

    float* out_ls   = (float*)d_out;          // [9510,2] fp32
    float* out_beta = (float*)d_out + 19020;  // [4096,2,1] fp32

    // ---- workspace carve (~109 MB) ----
    char* wp = (char*)d_ws;
    auto carve = [&](size_t bytes) { char* p = wp; wp += (bytes + 255) & ~(size_t)255; return p; };
    float* stats = (float*)carve(4096);
    int*   flag  = (int*)carve(256);
    float* dinv  = (float*)carve((size_t)NM * 4);
    float* cntK  = (float*)carve((size_t)8 * NKG * 4);
    float* part1 = (float*)carve((size_t)256 * 512 * 4);   // 0.5 MB
    float* part2 = (float*)carve((size_t)256 * 512 * 4);   // 0.5 MB
    int*   sbt   = (int*)carve(256);                       // block sums (<=33)
    int*   sbo   = (int*)carve(256);
    float* Wpool = (float*)carve((size_t)1630000 * 4);     // 6.5 MB fp32 weights
    float* fpb   = (float*)carve((size_t)ND * 256 * 4);
    float* gout  = (float*)carve((size_t)ND * 256 * 4);
    int* mdeg = (int*)carve((size_t)NM * 4);
    int* moff = (int*)carve((size_t)(NM + 1) * 4);
    int* mcur = (int*)carve((size_t)NM * 4);
    int* mbins= (int*)carve((size_t)EM * 4);
    int* kdeg = (int*)carve((size_t)NKG * 4);
    int* koff = (int*)carve((size_t)(NKG + 1) * 4);
    int* kcur = (int*)carve((size_t)NKG * 4);
    int* kbins= (int*)carve((size_t)EK * 4);
    int* pdeg = (int*)carve((size_t)ND * 4);
    int* poff = (int*)carve((size_t)(ND + 1) * 4);
    int* pcur = (int*)carve((size_t)ND * 4);
    int* pbins= (int*)carve((size_t)NM * 4);
    char*  REG1  = carve((size_t)NM * 128 * 2);            // 33.6 MB
    char*  REG2  = carve((size_t)NM * 64 * 4);             // 33.6 MB
    u16*   HB    = (u16*)carve((size_t)NM * 64 * 2);       // 16.8 MB

    float* fp1 = (float*)REG1;
    u16*   G1  = (u16*)REG1;
    float* xkg = (float*)REG1;
    float* x2  = xkg + (size_t)NKG * 256;
    float* x3  = x2  + (size_t)NKG * 256;
    float* x4  = x3  + (size_t)NKG * 128;
    float* BIG = (float*)REG2;                 // [NM,64] fp32
    float* HR  = (float*)REG2;                 // [8,NKG,64] fp32

    // ---- dtype detection + parameter conversion ----
    zero_int<<<1, 1, 0, stream>>>(flag);
    detect_f32<<<1024, 256, 0, stream>>>((const u16*)fp_data, (long)ND * 1024, flag);
    size_t woff = 0;
    auto conv = [&](int idx, long n) {
        float* dst = Wpool + woff; woff += (size_t)n;
        conv_in<<<256, 256, 0, stream>>>(d_in[idx], dst, n, flag);
        return dst;
    };
    float* fp_w1c   = conv(6,  1024L * 512);
    float* fp_w2c   = conv(8,  512L * 256);
    float* gcn_w1c  = conv(10, 64L * 128);
    float* gcn_w2c  = conv(12, 128L * 256);
    float* att_w1c  = conv(14, 256L * 128);
    float* att_b1c  = conv(15, 128);
    float* att_w2c  = conv(16, 128);
    float* rg_w1c   = conv(18, 8L * 256 * 256);
    float* rg_root1c= conv(19, 256L * 256);
    float* rg_w2c   = conv(21, 8L * 256 * 128);
    float* rg_root2c= conv(22, 256L * 128);
    float* lin1_wc  = conv(24, 128L * 64);
    float* lin2_wc  = conv(26, 64L * 2);
    float* lin2_bc  = conv(27, 2);

    // ---- CSR builds (3-kernel scans) ----
    auto scan = [&](const int* deg, int* off, int n) {
        int nb = divup(n, 4096);
        scan_bsum<<<nb, 1024, 0, stream>>>(deg, n, sbt);
        scan_tiny<<<1, 64, 0, stream>>>(sbt, nb, sbo);
        scan_final<<<nb, 1024, 0, stream>>>(deg, n, sbo, nb, off);
    };
    filli<<<512, 256, 0, stream>>>(mdeg, NM, 0);
    hist_int<<<2048, 256, 0, stream>>>(mol_dst, EM, mdeg);
    scan(mdeg, moff, NM);
    filli<<<512, 256, 0, stream>>>(mcur, NM, 0);
    bin_by<<<2048, 256, 0, stream>>>(mol_dst, EM, moff, mcur, mbins);
    dinv_from_deg<<<512, 256, 0, stream>>>(mdeg, dinv, NM);

    filli<<<64, 256, 0, stream>>>(kdeg, NKG, 0);
    hist_int<<<2048, 256, 0, stream>>>(kg_dst, EK, kdeg);
    scan(kdeg, koff, NKG);
    filli<<<64, 256, 0, stream>>>(kcur, NKG, 0);
    bin_by<<<2048, 256, 0, stream>>>(kg_dst, EK, koff, kcur, kbins);
    fillf<<<128, 256, 0, stream>>>(cntK, (long)8 * NKG, 0.f);
    kg_cnt<<<2048, 256, 0, stream>>>(kg_dst, kg_et, EK, NKG, cntK);

    filli<<<16, 256, 0, stream>>>(pdeg, ND, 0);
    hist_int<<<512, 256, 0, stream>>>(mol_batch, NM, pdeg);
    scan(pdeg, poff, ND);
    filli<<<16, 256, 0, stream>>>(pcur, ND, 0);
    bin_by<<<512, 256, 0, stream>>>(mol_batch, NM, poff, pcur, pbins);

    // ---- batch-norm helpers (atomic-free 2-pass stats) ----
    auto bn_stats = [&](const float* X, int M, int N, int lgN) {
        int bs = (N >= 512) ? 512 : 256;
        int G  = bs >> lgN;               // row-groups per block
        colstats_part<<<256, bs, 0, stream>>>(X, M, N, lgN, G, part1, part2);
        colstats_reduce<<<1, N, 0, stream>>>(part1, part2, 256, N, 1.0f / M,
                                             stats, stats + 512);
    };
    auto batchnorm = [&](float* X, int M, int N, int lgN) {
        bn_stats(X, M, N, lgN);
        long total = (long)M * N;
        int g = divup(total, 256); if (g > 8192) g = 8192;
        bn_apply<<<g, 256, 0, stream>>>(X, total, N - 1, stats, stats + 512, 1);
    };

    // ---------- fingerprint MLP branch ----------
    gemm64<2, float><<<dim3(64, 8, 1), 256, 0, stream>>>(
        fp_data, 1024, fp_w1c, 512, fp1, 512, ND, 512, 1024, 0, 0, flag);
    batchnorm(fp1, ND, 512, 9);
    gemm64<0, float><<<dim3(64, 4, 1), 256, 0, stream>>>(
        fp1, 512, fp_w2c, 256, fpb, 256, ND, 256, 512, 0, 0, nullptr);
    batchnorm(fpb, ND, 256, 8);

    // ---------- molecular GCN layer 1 (64 -> 128), two 64-col chunks --------
    for (int c0 = 0; c0 < 128; c0 += 64) {
        gemm64<2, u16><<<dim3(2048, 1, 1), 256, 0, stream>>>(
            mol_x, 64, gcn_w1c + c0, 128, HB, 64, NM, 64, 64, 0, 0, flag);
        mol_aggregate<<<32768, 256, 0, stream>>>(HB, dinv, moff, mbins, mol_src, NM, BIG);
        bn_stats(BIG, NM, 64, 6);
        bn_chunk_bf16<<<8192, 256, 0, stream>>>(BIG, (long)NM * 64, stats, stats + 512, G1, c0);
    }

    // ---------- molecular GCN layer 2 (128 -> 256) + fused BN + mean pool ---
    for (int c0 = 0; c0 < 256; c0 += 64) {
        gemm64<1, u16><<<dim3(2048, 1, 1), 256, 0, stream>>>(
            G1, 128, gcn_w2c + c0, 256, HB, 64, NM, 64, 128, 0, 0, nullptr);
        mol_aggregate<<<32768, 256, 0, stream>>>(HB, dinv, moff, mbins, mol_src, NM, BIG);
        bn_stats(BIG, NM, 64, 6);
        pool_aggregate_bn<<<1024, 256, 0, stream>>>(BIG, poff, pbins, ND,
                                                    stats, stats + 512, gout, c0);
    }

    // ---------- attention fusion (emb -> xkg rows [0,ND)) -------------------
    attention_fuse<<<ND, 128, 0, stream>>>(gout, fpb, att_w1c, att_b1c, att_w2c, xkg, out_beta);
    conv_in<<<512, 256, 0, stream>>>(d_in[17], xkg + (long)ND * 256, (long)NGENE * 256, flag);

    // ---------- RGCN layer 1 (256 -> 256) ----------
    gemm64<0, float><<<dim3(divup(NKG, 64), 4, 1), 256, 0, stream>>>(
        xkg, 256, rg_root1c, 256, x2, 256, NKG, 256, 256, 0, 0, nullptr);
    for (int c0 = 0; c0 < 256; c0 += 64) {
        gemm64<0, float><<<dim3(divup(NKG, 64), 1, 8), 256, 0, stream>>>(
            xkg, 256, rg_w1c + c0, 256, HR, 64, NKG, 64, 256,
            (long)256 * 256, (long)NKG * 64, nullptr);
        rgcn_aggregate<<<2378, 256, 0, stream>>>(HR, koff, kbins, kg_src, kg_et, cntK,
                                                 NKG, x2, 256, c0);
    }
    batchnorm(x2, NKG, 256, 8);

    // ---------- RGCN layer 2 (256 -> 128) ----------
    gemm64<0, float><<<dim3(divup(NKG, 64), 2, 1), 256, 0, stream>>>(
        x2, 256, rg_root2c, 128, x3, 128, NKG, 128, 256, 0, 0, nullptr);
    for (int c0 = 0; c0 < 128; c0 += 64) {
        gemm64<0, float><<<dim3(divup(NKG, 64), 1, 8), 256, 0, stream>>>(
            x2, 256, rg_w2c + c0, 128, HR, 64, NKG, 64, 256,
            (long)256 * 128, (long)NKG * 64, nullptr);
        rgcn_aggregate<<<2378, 256, 0, stream>>>(HR, koff, kbins, kg_src, kg_et, cntK,
                                                 NKG, x3, 128, c0);
    }
    batchnorm(x3, NKG, 128, 7);

    // ---------- classifier head (BN of x4 fused into logits) ----------
    gemm64<0, float><<<dim3(divup(NKG, 64), 1, 1), 256, 0, stream>>>(
        x3, 128, lin1_wc, 64, x4, 64, NKG, 64, 128, 0, 0, nullptr);
    bn_stats(x4, NKG, 64, 6);
    logits_out_bn<<<divup(NKG, 256), 256, 0, stream>>>(x4, stats, stats + 512,
                                                       lin2_wc, lin2_bc, out_ls, NKG);
}

// Round 9
// 2309.387 us; speedup vs baseline: 11.7676x; 1.2399x over previous
//
#include <hip/hip_runtime.h>
#include <hip/hip_bf16.h>
#include <cstdint>

typedef __hip_bfloat16 bf16;
typedef unsigned short u16;
typedef unsigned int u32;

__device__ __forceinline__ float tofloat(float x){ return x; }
__device__ __forceinline__ float tofloat(bf16 x){ return __bfloat162float(x); }
__device__ __forceinline__ float b2f(u16 a){ return __uint_as_float(((unsigned)a) << 16); }
__device__ __forceinline__ u16 f2b(float f){           // round-to-nearest-even
    unsigned u = __float_as_uint(f);
    return (u16)((u + 0x7FFFu + ((u >> 16) & 1u)) >> 16);
}
__device__ __forceinline__ void store4(float* p, float a, float b, float c, float d){
    *(float4*)p = make_float4(a, b, c, d);
}
__device__ __forceinline__ void store4(u16* p, float a, float b, float c, float d){
    ushort4 v; v.x = f2b(a); v.y = f2b(b); v.z = f2b(c); v.w = f2b(d);
    *(ushort4*)p = v;
}

static inline int divup(long a, long b){ return (int)((a + b - 1) / b); }

// ---------------- input dtype detection -------------------------------------
__global__ void zero_int(int* p){ *p = 0; }

__global__ void detect_f32(const u16* __restrict__ h, long n, int* flag)
{
    long i = (long)blockIdx.x * blockDim.x + threadIdx.x;
    long st = (long)gridDim.x * blockDim.x;
    int c = 0;
    for (; i < n; i += st)
        if (((h[i] >> 7) & 0xFF) == 0xFF) c++;
    if (c) atomicAdd(flag, c);
}

// single launch converting all weight tensors
struct ConvTab { const void* src[14]; float* dst[14]; int n[14]; };

__global__ void conv_all(ConvTab t, const int* __restrict__ flagp)
{
    bool f32 = (*flagp != 0);
    int seg = blockIdx.y;
    const void* s = t.src[seg];
    float* d = t.dst[seg];
    int n = t.n[seg];
    long i = (long)blockIdx.x * blockDim.x + threadIdx.x;
    long st = (long)gridDim.x * blockDim.x;
    for (; i < n; i += st)
        d[i] = f32 ? ((const float*)s)[i] : tofloat(((const bf16*)s)[i]);
}

__global__ void conv_in(const void* __restrict__ src, float* __restrict__ dst,
                        long n, const int* __restrict__ flagp)
{
    bool f32 = (*flagp != 0);
    long i = (long)blockIdx.x * blockDim.x + threadIdx.x;
    long st = (long)gridDim.x * blockDim.x;
    for (; i < n; i += st)
        dst[i] = f32 ? ((const float*)src)[i] : tofloat(((const bf16*)src)[i]);
}

// ---------------- 64x64-tile GEMM, 256 thr, 4x4 micro-tile ------------------
template<int AM, typename TC>
__global__ __launch_bounds__(256)
void gemm64(const void* __restrict__ A_, int lda,
            const float* __restrict__ B, int ldb,
            TC* __restrict__ C, int ldc,
            int M, int N, int K, long sB, long sC,
            const int* __restrict__ flagp)
{
    bool af32 = (AM == 0);
    if (AM == 2) af32 = (*flagp != 0);
    const float* Af = (const float*)A_;
    const u16*   Au = (const u16*)A_;
    const float* Bp = B + (long)blockIdx.z * sB;
    TC*          Cp = C + (long)blockIdx.z * sC;

    __shared__ float As[16][68];
    __shared__ float Bs[16][68];

    const int tid = threadIdx.x;
    const int row0 = blockIdx.x * 64, col0 = blockIdx.y * 64;

    float acc[4][4];
#pragma unroll
    for (int i = 0; i < 4; i++)
#pragma unroll
        for (int j = 0; j < 4; j++) acc[i][j] = 0.f;

    const int ar = tid >> 2;
    const int ak = (tid & 3) * 4;
    const int bk = tid >> 4;
    const int bc = (tid & 15) * 4;
    const int ty4 = (tid >> 4) * 4, tx4 = (tid & 15) * 4;

    for (int k0 = 0; k0 < K; k0 += 16) {
        {
            int row = row0 + ar;
            float x0 = 0.f, x1 = 0.f, x2 = 0.f, x3 = 0.f;
            if (row < M) {
                long base = (long)row * lda + k0 + ak;
                if (af32) {
                    float4 v = *(const float4*)(Af + base);
                    x0 = v.x; x1 = v.y; x2 = v.z; x3 = v.w;
                } else {
                    ushort4 u = *(const ushort4*)(Au + base);
                    x0 = b2f(u.x); x1 = b2f(u.y); x2 = b2f(u.z); x3 = b2f(u.w);
                }
            }
            As[ak + 0][ar] = x0; As[ak + 1][ar] = x1;
            As[ak + 2][ar] = x2; As[ak + 3][ar] = x3;
        }
        {
            int c = col0 + bc;
            float4 v = make_float4(0.f, 0.f, 0.f, 0.f);
            if (c < N) v = *(const float4*)(Bp + (long)(k0 + bk) * ldb + c);
            *(float4*)&Bs[bk][bc] = v;
        }
        __syncthreads();
#pragma unroll
        for (int k = 0; k < 16; k++) {
            float4 a = *(const float4*)&As[k][ty4];
            float4 b = *(const float4*)&Bs[k][tx4];
            acc[0][0] += a.x * b.x; acc[0][1] += a.x * b.y; acc[0][2] += a.x * b.z; acc[0][3] += a.x * b.w;
            acc[1][0] += a.y * b.x; acc[1][1] += a.y * b.y; acc[1][2] += a.y * b.z; acc[1][3] += a.y * b.w;
            acc[2][0] += a.z * b.x; acc[2][1] += a.z * b.y; acc[2][2] += a.z * b.z; acc[2][3] += a.z * b.w;
            acc[3][0] += a.w * b.x; acc[3][1] += a.w * b.y; acc[3][2] += a.w * b.z; acc[3][3] += a.w * b.w;
        }
        __syncthreads();
    }

    int c = col0 + tx4;
#pragma unroll
    for (int i = 0; i < 4; i++) {
        int r = row0 + ty4 + i;
        if (r < M && c < N)
            store4(&Cp[(long)r * ldc + c], acc[i][0], acc[i][1], acc[i][2], acc[i][3]);
    }
}

// ---------------- utility ---------------------------------------------------
__global__ void filli(int* p, long n, int v)
{
    long i = (long)blockIdx.x * blockDim.x + threadIdx.x;
    long st = (long)gridDim.x * blockDim.x;
    for (; i < n; i += st) p[i] = v;
}

// ---------------- CSR build pieces ------------------------------------------
__global__ void hist_int(const int* __restrict__ key, long n, int* __restrict__ h)
{
    long i = (long)blockIdx.x * blockDim.x + threadIdx.x;
    long st = (long)gridDim.x * blockDim.x;
    for (; i < n; i += st) atomicAdd(&h[key[i]], 1);
}

__global__ __launch_bounds__(1024)
void scan_bsum(const int* __restrict__ in, int n, int* __restrict__ btot)
{
    __shared__ int sh[1024];
    int tid = threadIdx.x;
    int i0 = blockIdx.x * 4096 + tid * 4;
    int s = 0;
#pragma unroll
    for (int t = 0; t < 4; t++) { int idx = i0 + t; s += (idx < n) ? in[idx] : 0; }
    sh[tid] = s;
    __syncthreads();
    for (int off = 512; off > 0; off >>= 1) {
        if (tid < off) sh[tid] += sh[tid + off];
        __syncthreads();
    }
    if (tid == 0) btot[blockIdx.x] = sh[0];
}

__global__ void scan_tiny(const int* __restrict__ btot, int nb, int* __restrict__ boff)
{
    if (threadIdx.x == 0) {
        int c = 0;
        for (int b = 0; b < nb; b++) { boff[b] = c; c += btot[b]; }
        boff[nb] = c;
    }
}

__global__ __launch_bounds__(1024)
void scan_final(const int* __restrict__ in, int n, const int* __restrict__ boff,
                int nb, int* __restrict__ out)
{
    __shared__ int buf[1024];
    int tid = threadIdx.x;
    int i0 = blockIdx.x * 4096 + tid * 4;
    int v[4]; int s = 0;
#pragma unroll
    for (int t = 0; t < 4; t++) {
        int idx = i0 + t;
        v[t] = (idx < n) ? in[idx] : 0;
        s += v[t];
    }
    buf[tid] = s;
    __syncthreads();
    for (int off = 1; off < 1024; off <<= 1) {
        int t = (tid >= off) ? buf[tid - off] : 0;
        __syncthreads();
        buf[tid] += t;
        __syncthreads();
    }
    int excl = buf[tid] - s + boff[blockIdx.x];
#pragma unroll
    for (int t = 0; t < 4; t++) {
        int idx = i0 + t;
        if (idx < n) out[idx] = excl;
        excl += v[t];
    }
    if (blockIdx.x == 0 && tid == 0) out[n] = boff[nb];
}

__global__ void bin_by(const int* __restrict__ key, long n,
                       const int* __restrict__ off, int* __restrict__ cursor,
                       int* __restrict__ bins)
{
    long i = (long)blockIdx.x * blockDim.x + threadIdx.x;
    long st = (long)gridDim.x * blockDim.x;
    for (; i < n; i += st) {
        int k = key[i];
        int pos = off[k] + atomicAdd(&cursor[k], 1);
        bins[pos] = (int)i;
    }
}

__global__ void dinv_from_deg(const int* __restrict__ deg, float* __restrict__ dinv, long n)
{
    long i = (long)blockIdx.x * blockDim.x + threadIdx.x;
    long st = (long)gridDim.x * blockDim.x;
    for (; i < n; i += st) dinv[i] = rsqrtf((float)(deg[i] + 1));
}

__global__ void kg_cnt(const int* __restrict__ dst, const int* __restrict__ et,
                       long E, int NKG, float* cnt)
{
    long i = (long)blockIdx.x * blockDim.x + threadIdx.x;
    long st = (long)gridDim.x * blockDim.x;
    for (; i < E; i += st) atomicAdd(&cnt[(long)et[i] * NKG + dst[i]], 1.0f);
}

__global__ void kg_enorm(const int* __restrict__ dst, const int* __restrict__ et,
                         const float* __restrict__ cnt, long E, int NKG,
                         float* __restrict__ en)
{
    long i = (long)blockIdx.x * blockDim.x + threadIdx.x;
    long st = (long)gridDim.x * blockDim.x;
    for (; i < E; i += st)
        en[i] = 1.0f / fmaxf(cnt[(long)et[i] * NKG + dst[i]], 1.0f);
}

__global__ void mol_enorm(const int* __restrict__ src, const int* __restrict__ dst,
                          const float* __restrict__ dinv, long E, float* __restrict__ en)
{
    long i = (long)blockIdx.x * blockDim.x + threadIdx.x;
    long st = (long)gridDim.x * blockDim.x;
    for (; i < E; i += st) en[i] = dinv[src[i]] * dinv[dst[i]];
}

// ---------------- batch-norm stats (2-pass, 64 partial blocks) --------------
__global__ __launch_bounds__(512)
void colstats_part(const float* __restrict__ X, int M, int N, int lgN, int G,
                   float* __restrict__ p1, float* __restrict__ p2)
{
    __shared__ float sh1[512], sh2[512];
    int tid = threadIdx.x;
    int col = tid & (N - 1);
    int grp = tid >> lgN;
    float s1 = 0.f, s2 = 0.f;
    for (long row = (long)blockIdx.x * G + grp; row < M; row += (long)gridDim.x * G) {
        float v = X[row * N + col];
        s1 += v; s2 += v * v;
    }
    sh1[tid] = s1; sh2[tid] = s2;
    __syncthreads();
    if (grp == 0) {
        for (int g = 1; g < G; g++) { s1 += sh1[col + (g << lgN)]; s2 += sh2[col + (g << lgN)]; }
        p1[blockIdx.x * N + col] = s1;
        p2[blockIdx.x * N + col] = s2;
    }
}

// bf16 strided chunk variant: X[row*ld + c0 + col], 64 cols
__global__ __launch_bounds__(512)
void colstats_part_b16(const u16* __restrict__ X, int M, int ld, int c0,
                       float* __restrict__ p1, float* __restrict__ p2)
{
    __shared__ float sh1[512], sh2[512];
    int tid = threadIdx.x;
    int col = tid & 63;
    int grp = tid >> 6;                      // 8 groups
    float s1 = 0.f, s2 = 0.f;
    for (long row = (long)blockIdx.x * 8 + grp; row < M; row += (long)gridDim.x * 8) {
        float v = b2f(X[row * ld + c0 + col]);
        s1 += v; s2 += v * v;
    }
    sh1[tid] = s1; sh2[tid] = s2;
    __syncthreads();
    if (grp == 0) {
        for (int g = 1; g < 8; g++) { s1 += sh1[col + (g << 6)]; s2 += sh2[col + (g << 6)]; }
        p1[blockIdx.x * 64 + col] = s1;
        p2[blockIdx.x * 64 + col] = s2;
    }
}

__global__ void colstats_reduce(const float* __restrict__ p1, const float* __restrict__ p2,
                                int nblk, int N, float invM,
                                float* __restrict__ s1o, float* __restrict__ s2o)
{
    int j = threadIdx.x;
    if (j >= N) return;
    float a = 0.f, c = 0.f;
    for (int b = 0; b < nblk; b += 4) {
        a += p1[(b + 0) * N + j] + p1[(b + 1) * N + j] + p1[(b + 2) * N + j] + p1[(b + 3) * N + j];
        c += p2[(b + 0) * N + j] + p2[(b + 1) * N + j] + p2[(b + 2) * N + j] + p2[(b + 3) * N + j];
    }
    float mean = a * invM;
    float var  = fmaxf(c * invM - mean * mean, 0.f);
    s1o[j] = mean;
    s2o[j] = rsqrtf(var + 1e-5f);
}

__global__ void bn_apply(float* X, long total, int mask,
                         const float* __restrict__ s1, const float* __restrict__ s2)
{
    long i = (long)blockIdx.x * blockDim.x + threadIdx.x;
    long st = (long)gridDim.x * blockDim.x;
    for (; i < total; i += st) {
        int j = (int)(i & mask);
        X[i] = fmaxf((X[i] - s1[j]) * s2[j], 0.f);
    }
}

// BN+ReLU in place on bf16 strided chunk [M,64] at X[n*ld + c0 + f]
__global__ void bn_apply_b16(u16* __restrict__ X, long total, int ld, int c0,
                             const float* __restrict__ s1, const float* __restrict__ s2)
{
    long i = (long)blockIdx.x * blockDim.x + threadIdx.x;
    long st = (long)gridDim.x * blockDim.x;
    for (; i < total; i += st) {
        long n = i >> 6;
        int  f = (int)(i & 63);
        u16* p = X + n * ld + c0 + f;
        *p = f2b(fmaxf((b2f(*p) - s1[f]) * s2[f], 0.f));
    }
}

// ---------------- CSR aggregation kernels (no atomics) ----------------------
// TOBF=1: write bf16 into outb[n*128 + c0 + lane]; else fp32 outf[n*64+lane]
template<int TOBF>
__global__ __launch_bounds__(256)
void mol_aggregate(const u16* __restrict__ hb, const float* __restrict__ dinv,
                   const int* __restrict__ off, const int* __restrict__ bins,
                   const int* __restrict__ src, const float* __restrict__ en,
                   int NM, float* __restrict__ outf, u16* __restrict__ outb, int c0)
{
    int wid  = (int)(((long)blockIdx.x * 256 + threadIdx.x) >> 6);
    int lane = threadIdx.x & 63;
    if (wid >= NM) return;
    float dv = dinv[wid];
    float acc = b2f(hb[(long)wid * 64 + lane]) * dv * dv;
    int j = off[wid], j1 = off[wid + 1];
    for (; j + 1 < j1; j += 2) {
        int e0 = bins[j], e1 = bins[j + 1];
        int s0 = src[e0], s1 = src[e1];
        float n0 = en[e0], n1 = en[e1];
        float h0 = b2f(hb[(long)s0 * 64 + lane]);
        float h1 = b2f(hb[(long)s1 * 64 + lane]);
        acc += h0 * n0 + h1 * n1;
    }
    if (j < j1) {
        int e = bins[j];
        acc += b2f(hb[(long)src[e] * 64 + lane]) * en[e];
    }
    if (TOBF) outb[(long)wid * 128 + c0 + lane] = f2b(acc);
    else      outf[(long)wid * 64 + lane] = acc;
}

// RGCN 128-wide: hr bf16 [8,NKG,128]; lane covers cols 2l,2l+1 via one uint
__global__ __launch_bounds__(256)
void rgcn_agg128(const u16* __restrict__ hr, const int* __restrict__ off,
                 const int* __restrict__ bins, const int* __restrict__ src,
                 const int* __restrict__ et, const float* __restrict__ en,
                 int NKG, float* __restrict__ out, int ldout, int c0)
{
    int wid  = (int)(((long)blockIdx.x * 256 + threadIdx.x) >> 6);
    int lane = threadIdx.x & 63;
    if (wid >= NKG) return;
    float a0 = 0.f, a1 = 0.f;
    int j = off[wid], j1 = off[wid + 1];
    for (; j + 1 < j1; j += 2) {
        int e0 = bins[j], e1 = bins[j + 1];
        int r0 = et[e0], s0 = src[e0];
        int r1 = et[e1], s1 = src[e1];
        float n0 = en[e0], n1 = en[e1];
        u32 u0 = *(const u32*)(hr + ((long)r0 * NKG + s0) * 128 + 2 * lane);
        u32 u1 = *(const u32*)(hr + ((long)r1 * NKG + s1) * 128 + 2 * lane);
        a0 += b2f((u16)(u0 & 0xFFFF)) * n0 + b2f((u16)(u1 & 0xFFFF)) * n1;
        a1 += b2f((u16)(u0 >> 16)) * n0 + b2f((u16)(u1 >> 16)) * n1;
    }
    if (j < j1) {
        int e = bins[j];
        u32 u0 = *(const u32*)(hr + ((long)et[e] * NKG + src[e]) * 128 + 2 * lane);
        float n0 = en[e];
        a0 += b2f((u16)(u0 & 0xFFFF)) * n0;
        a1 += b2f((u16)(u0 >> 16)) * n0;
    }
    float2* o = (float2*)(out + (long)wid * ldout + c0 + 2 * lane);
    float2 v = *o; v.x += a0; v.y += a1; *o = v;
}

// mean-pool with fused BN+ReLU of the source chunk (BIG fp32 [NM,64])
__global__ __launch_bounds__(256)
void pool_aggregate_bn(const float* __restrict__ g, const int* __restrict__ off,
                       const int* __restrict__ bins, int ND,
                       const float* __restrict__ s1, const float* __restrict__ s2,
                       float* __restrict__ gout, int c0)
{
    int wid  = (int)(((long)blockIdx.x * 256 + threadIdx.x) >> 6);
    int lane = threadIdx.x & 63;
    if (wid >= ND) return;
    float m = s1[lane], r = s2[lane];
    int j0 = off[wid], j1 = off[wid + 1];
    float acc = 0.f;
    for (int j = j0; j < j1; j++)
        acc += fmaxf((g[(long)bins[j] * 64 + lane] - m) * r, 0.f);
    float c = fmaxf((float)(j1 - j0), 1.0f);
    gout[(long)wid * 256 + c0 + lane] = acc / c;
}

// ---------------- attention fusion ------------------------------------------
__global__ void attention_fuse(const float* __restrict__ go, const float* __restrict__ fpv,
                               const float* __restrict__ W1, const float* __restrict__ B1,
                               const float* __restrict__ W2,
                               float* __restrict__ emb, float* __restrict__ beta_out)
{
    int d = blockIdx.x;
    int t = threadIdx.x;
    __shared__ float z[2][256];
    __shared__ float red[128];
    for (int c = t; c < 256; c += 128) {
        z[0][c] = go[(long)d * 256 + c];
        z[1][c] = fpv[(long)d * 256 + c];
    }
    __syncthreads();
    float s[2];
    for (int v = 0; v < 2; v++) {
        float acc = B1[t];
        for (int k = 0; k < 256; k++) acc += z[v][k] * W1[k * 128 + t];
        red[t] = tanhf(acc) * W2[t];
        __syncthreads();
        for (int off = 64; off > 0; off >>= 1) {
            if (t < off) red[t] += red[t + off];
            __syncthreads();
        }
        s[v] = red[0];
        __syncthreads();
    }
    float m = fmaxf(s[0], s[1]);
    float e0 = expf(s[0] - m), e1 = expf(s[1] - m);
    float inv = 1.0f / (e0 + e1);
    float b0 = e0 * inv, b1 = e1 * inv;
    for (int c = t; c < 256; c += 128)
        emb[(long)d * 256 + c] = b0 * z[0][c] + b1 * z[1][c];
    if (t == 0) {
        beta_out[d * 2 + 0] = b0;
        beta_out[d * 2 + 1] = b1;
    }
}

// ---------------- final linear + log_softmax, fused BN on x4 ----------------
__global__ void logits_out_bn(const float* __restrict__ x4,
                              const float* __restrict__ s1, const float* __restrict__ s2,
                              const float* __restrict__ w, const float* __restrict__ b,
                              float* __restrict__ out, int NKG)
{
    int i = blockIdx.x * blockDim.x + threadIdx.x;
    if (i >= NKG) return;
    float a0 = b[0], a1 = b[1];
    for (int k = 0; k < 64; k++) {
        float v = fmaxf((x4[(long)i * 64 + k] - s1[k]) * s2[k], 0.f);
        a0 += v * w[k * 2 + 0];
        a1 += v * w[k * 2 + 1];
    }
    float m = fmaxf(a0, a1);
    float lse = m + logf(expf(a0 - m) + expf(a1 - m));
    out[i * 2 + 0] = a0 - lse;
    out[i * 2 + 1] = a1 - lse;
}

// ============================================================================
extern "C" void kernel_launch(void* const* d_in, const int* in_sizes, int n_in,
                              void* d_out, int out_size, void* d_ws, size_t ws_size,
                              hipStream_t stream)
{
    (void)in_sizes; (void)n_in; (void)out_size; (void)ws_size;
    const int ND = 4096, NM = 131072, NKG = 9510, NGENE = 5414;
    const long EM = 524288, EK = 524288;

    const void* fp_data = d_in[0];
    const void* mol_x   = d_in[1];
    const int*  mol_batch = (const int*)d_in[2];
    const int*  mol_ei  = (const int*)d_in[3];
    const int*  kg_ei   = (const int*)d_in[4];
    const int*  kg_et   = (const int*)d_in[5];

    const int* mol_src = mol_ei;
    const int* mol_dst = mol_ei + EM;
    const int* kg_src  = kg_ei;
    const int* kg_dst  = kg_ei + EK;

    float* out_ls   = (float*)d_out;          // [9510,2] fp32
    float* out_beta = (float*)d_out + 19020;  // [4096,2,1] fp32

    // ---- workspace carve (~113 MB) ----
    char* wp = (char*)d_ws;
    auto carve = [&](size_t bytes) { char* p = wp; wp += (bytes + 255) & ~(size_t)255; return p; };
    float* stats = (float*)carve(4096);
    int*   flag  = (int*)carve(256);
    float* dinv  = (float*)carve((size_t)NM * 4);
    float* enM   = (float*)carve((size_t)EM * 4);          // 2 MB edge norms
    float* enK   = (float*)carve((size_t)EK * 4);          // 2 MB
    float* part1 = (float*)carve((size_t)64 * 512 * 4);
    float* part2 = (float*)carve((size_t)64 * 512 * 4);
    int*   sbt   = (int*)carve(256);
    int*   sbo   = (int*)carve(256);
    float* Wpool = (float*)carve((size_t)1630000 * 4);     // 6.5 MB fp32 weights
    float* fpb   = (float*)carve((size_t)ND * 256 * 4);
    float* gout  = (float*)carve((size_t)ND * 256 * 4);
    // zero-span: cntK + all deg/cur arrays contiguous
    char*  z0    = wp;
    float* cntK  = (float*)carve((size_t)8 * NKG * 4);
    int* mdeg = (int*)carve((size_t)NM * 4);
    int* mcur = (int*)carve((size_t)NM * 4);
    int* kdeg = (int*)carve((size_t)NKG * 4);
    int* kcur = (int*)carve((size_t)NKG * 4);
    int* pdeg = (int*)carve((size_t)ND * 4);
    int* pcur = (int*)carve((size_t)ND * 4);
    char*  z1    = wp;
    int* moff = (int*)carve((size_t)(NM + 1) * 4);
    int* mbins= (int*)carve((size_t)EM * 4);
    int* koff = (int*)carve((size_t)(NKG + 1) * 4);
    int* kbins= (int*)carve((size_t)EK * 4);
    int* poff = (int*)carve((size_t)(ND + 1) * 4);
    int* pbins= (int*)carve((size_t)NM * 4);
    char*  REG1  = carve((size_t)NM * 128 * 2);            // 33.6 MB
    char*  REG2  = carve((size_t)NM * 64 * 4);             // 33.6 MB
    u16*   HB    = (u16*)carve((size_t)NM * 64 * 2);       // 16.8 MB

    float* fp1 = (float*)REG1;                 // fp phase
    u16*   G1  = (u16*)REG1;                   // [NM,128] bf16 mol phase
    float* xkg = (float*)REG1;                 // RGCN phase
    float* x2  = xkg + (size_t)NKG * 256;
    float* x3  = x2  + (size_t)NKG * 256;
    float* x4  = x3  + (size_t)NKG * 128;
    float* BIG = (float*)REG2;                 // [NM,64] fp32
    u16*   HR  = (u16*)REG2;                   // [8,NKG,128] bf16

    // ---- dtype detection + all weight conversions in one launch ----
    zero_int<<<1, 1, 0, stream>>>(flag);
    detect_f32<<<1024, 256, 0, stream>>>((const u16*)fp_data, (long)ND * 1024, flag);
    ConvTab tab;
    const int widx[14] = {6, 8, 10, 12, 14, 15, 16, 18, 19, 21, 22, 24, 26, 27};
    const int wn[14]   = {1024*512, 512*256, 64*128, 128*256, 256*128, 128, 128,
                          8*256*256, 256*256, 8*256*128, 256*128, 128*64, 64*2, 2};
    float* wptr[14];
    {
        size_t o = 0;
        for (int i = 0; i < 14; i++) {
            tab.src[i] = d_in[widx[i]];
            tab.dst[i] = Wpool + o;
            tab.n[i]   = wn[i];
            wptr[i]    = Wpool + o;
            o += (size_t)wn[i];
        }
    }
    conv_all<<<dim3(32, 14), 256, 0, stream>>>(tab, flag);
    float* fp_w1c = wptr[0],  *fp_w2c = wptr[1],  *gcn_w1c = wptr[2], *gcn_w2c = wptr[3];
    float* att_w1c = wptr[4], *att_b1c = wptr[5], *att_w2c = wptr[6];
    float* rg_w1c = wptr[7],  *rg_root1c = wptr[8], *rg_w2c = wptr[9], *rg_root2c = wptr[10];
    float* lin1_wc = wptr[11], *lin2_wc = wptr[12], *lin2_bc = wptr[13];

    // ---- CSR builds ----
    filli<<<512, 256, 0, stream>>>((int*)z0, (long)(z1 - z0) / 4, 0);
    auto scan = [&](const int* deg, int* off, int n) {
        int nb = divup(n, 4096);
        scan_bsum<<<nb, 1024, 0, stream>>>(deg, n, sbt);
        scan_tiny<<<1, 64, 0, stream>>>(sbt, nb, sbo);
        scan_final<<<nb, 1024, 0, stream>>>(deg, n, sbo, nb, off);
    };
    hist_int<<<2048, 256, 0, stream>>>(mol_dst, EM, mdeg);
    scan(mdeg, moff, NM);
    bin_by<<<2048, 256, 0, stream>>>(mol_dst, EM, moff, mcur, mbins);
    dinv_from_deg<<<512, 256, 0, stream>>>(mdeg, dinv, NM);
    mol_enorm<<<1024, 256, 0, stream>>>(mol_src, mol_dst, dinv, EM, enM);

    hist_int<<<2048, 256, 0, stream>>>(kg_dst, EK, kdeg);
    scan(kdeg, koff, NKG);
    bin_by<<<2048, 256, 0, stream>>>(kg_dst, EK, koff, kcur, kbins);
    kg_cnt<<<2048, 256, 0, stream>>>(kg_dst, kg_et, EK, NKG, cntK);
    kg_enorm<<<1024, 256, 0, stream>>>(kg_dst, kg_et, cntK, EK, NKG, enK);

    hist_int<<<512, 256, 0, stream>>>(mol_batch, NM, pdeg);
    scan(pdeg, poff, ND);
    bin_by<<<512, 256, 0, stream>>>(mol_batch, NM, poff, pcur, pbins);

    // ---- batch-norm helpers ----
    auto bn_stats = [&](const float* X, int M, int N, int lgN) {
        colstats_part<<<64, 512, 0, stream>>>(X, M, N, lgN, 512 >> lgN, part1, part2);
        colstats_reduce<<<1, N, 0, stream>>>(part1, part2, 64, N, 1.0f / M,
                                             stats, stats + 512);
    };
    auto batchnorm = [&](float* X, int M, int N, int lgN) {
        bn_stats(X, M, N, lgN);
        long total = (long)M * N;
        int g = divup(total, 256); if (g > 8192) g = 8192;
        bn_apply<<<g, 256, 0, stream>>>(X, total, N - 1, stats, stats + 512);
    };

    // ---------- fingerprint MLP branch ----------
    gemm64<2, float><<<dim3(64, 8, 1), 256, 0, stream>>>(
        fp_data, 1024, fp_w1c, 512, fp1, 512, ND, 512, 1024, 0, 0, flag);
    batchnorm(fp1, ND, 512, 9);
    gemm64<0, float><<<dim3(64, 4, 1), 256, 0, stream>>>(
        fp1, 512, fp_w2c, 256, fpb, 256, ND, 256, 512, 0, 0, nullptr);
    batchnorm(fpb, ND, 256, 8);

    // ---------- mol GCN layer 1 (64->128): agg writes bf16 straight to G1 ---
    for (int c0 = 0; c0 < 128; c0 += 64) {
        gemm64<2, u16><<<dim3(2048, 1, 1), 256, 0, stream>>>(
            mol_x, 64, gcn_w1c + c0, 128, HB, 64, NM, 64, 64, 0, 0, flag);
        mol_aggregate<1><<<32768, 256, 0, stream>>>(HB, dinv, moff, mbins, mol_src,
                                                    enM, NM, nullptr, G1, c0);
        colstats_part_b16<<<64, 512, 0, stream>>>(G1, NM, 128, c0, part1, part2);
        colstats_reduce<<<1, 64, 0, stream>>>(part1, part2, 64, 64, 1.0f / NM,
                                              stats, stats + 512);
        bn_apply_b16<<<8192, 256, 0, stream>>>(G1, (long)NM * 64, 128, c0,
                                               stats, stats + 512);
    }

    // ---------- mol GCN layer 2 (128->256) + fused BN + mean pool -----------
    for (int c0 = 0; c0 < 256; c0 += 64) {
        gemm64<1, u16><<<dim3(2048, 1, 1), 256, 0, stream>>>(
            G1, 128, gcn_w2c + c0, 256, HB, 64, NM, 64, 128, 0, 0, nullptr);
        mol_aggregate<0><<<32768, 256, 0, stream>>>(HB, dinv, moff, mbins, mol_src,
                                                    enM, NM, BIG, nullptr, 0);
        bn_stats(BIG, NM, 64, 6);
        pool_aggregate_bn<<<1024, 256, 0, stream>>>(BIG, poff, pbins, ND,
                                                    stats, stats + 512, gout, c0);
    }

    // ---------- attention fusion ----------
    attention_fuse<<<ND, 128, 0, stream>>>(gout, fpb, att_w1c, att_b1c, att_w2c, xkg, out_beta);
    conv_in<<<512, 256, 0, stream>>>(d_in[17], xkg + (long)ND * 256, (long)NGENE * 256, flag);

    // ---------- RGCN layer 1 (256 -> 256), two 128-wide chunks --------------
    gemm64<0, float><<<dim3(divup(NKG, 64), 4, 1), 256, 0, stream>>>(
        xkg, 256, rg_root1c, 256, x2, 256, NKG, 256, 256, 0, 0, nullptr);
    for (int c0 = 0; c0 < 256; c0 += 128) {
        gemm64<0, u16><<<dim3(divup(NKG, 64), 2, 8), 256, 0, stream>>>(
            xkg, 256, rg_w1c + c0, 256, HR, 128, NKG, 128, 256,
            (long)256 * 256, (long)NKG * 128, nullptr);
        rgcn_agg128<<<2378, 256, 0, stream>>>(HR, koff, kbins, kg_src, kg_et, enK,
                                              NKG, x2, 256, c0);
    }
    batchnorm(x2, NKG, 256, 8);

    // ---------- RGCN layer 2 (256 -> 128), one 128-wide chunk ---------------
    gemm64<0, float><<<dim3(divup(NKG, 64), 2, 1), 256, 0, stream>>>(
        x2, 256, rg_root2c, 128, x3, 128, NKG, 128, 256, 0, 0, nullptr);
    gemm64<0, u16><<<dim3(divup(NKG, 64), 2, 8), 256, 0, stream>>>(
        x2, 256, rg_w2c, 128, HR, 128, NKG, 128, 256,
        (long)256 * 128, (long)NKG * 128, nullptr);
    rgcn_agg128<<<2378, 256, 0, stream>>>(HR, koff, kbins, kg_src, kg_et, enK,
                                          NKG, x3, 128, 0);
    batchnorm(x3, NKG, 128, 7);

    // ---------- classifier head (BN of x4 fused into logits) ----------
    gemm64<0, float><<<dim3(divup(NKG, 64), 1, 1), 256, 0, stream>>>(
        x3, 128, lin1_wc, 64, x4, 64, NKG, 64, 128, 0, 0, nullptr);
    bn_stats(x4, NKG, 64, 6);
    logits_out_bn<<<divup(NKG, 256), 256, 0, stream>>>(x4, stats, stats + 512,
                                                       lin2_wc, lin2_bc, out_ls, NKG);
}

// Round 10
// 1847.317 us; speedup vs baseline: 14.7111x; 1.2501x over previous
//
#include <hip/hip_runtime.h>
#include <hip/hip_bf16.h>
#include <cstdint>

typedef __hip_bfloat16 bf16;
typedef unsigned short u16;
typedef unsigned int u32;
typedef __attribute__((ext_vector_type(8))) short short8;
typedef __attribute__((ext_vector_type(4))) float f32x4;

__device__ __forceinline__ float tofloat(float x){ return x; }
__device__ __forceinline__ float tofloat(bf16 x){ return __bfloat162float(x); }
__device__ __forceinline__ float b2f(u16 a){ return __uint_as_float(((unsigned)a) << 16); }
__device__ __forceinline__ u16 f2b(float f){           // round-to-nearest-even
    unsigned u = __float_as_uint(f);
    return (u16)((u + 0x7FFFu + ((u >> 16) & 1u)) >> 16);
}
__device__ __forceinline__ void storec(float* p, float v){ *p = v; }
__device__ __forceinline__ void storec(u16* p, float v){ *p = f2b(v); }

static inline int divup(long a, long b){ return (int)((a + b - 1) / b); }

// ---------------- input dtype detection -------------------------------------
__global__ void zero_int(int* p){ *p = 0; }

__global__ void detect_f32(const u16* __restrict__ h, long n, int* flag)
{
    long i = (long)blockIdx.x * blockDim.x + threadIdx.x;
    long st = (long)gridDim.x * blockDim.x;
    int c = 0;
    for (; i < n; i += st)
        if (((h[i] >> 7) & 0xFF) == 0xFF) c++;
    if (c) atomicAdd(flag, c);
}

// convert all weights: fp32 pool + bf16 pool in one launch
struct ConvTab { const void* src[14]; float* dst[14]; u16* dstB[14]; int n[14]; };

__global__ void conv_all(ConvTab t, const int* __restrict__ flagp)
{
    bool f32 = (*flagp != 0);
    int seg = blockIdx.y;
    const void* s = t.src[seg];
    float* d = t.dst[seg];
    u16*   dB = t.dstB[seg];
    int n = t.n[seg];
    long i = (long)blockIdx.x * blockDim.x + threadIdx.x;
    long st = (long)gridDim.x * blockDim.x;
    for (; i < n; i += st) {
        float v = f32 ? ((const float*)s)[i] : tofloat(((const bf16*)s)[i]);
        d[i] = v; dB[i] = f2b(v);
    }
}

__global__ void conv_in(const void* __restrict__ src, float* __restrict__ dst,
                        long n, const int* __restrict__ flagp)
{
    bool f32 = (*flagp != 0);
    long i = (long)blockIdx.x * blockDim.x + threadIdx.x;
    long st = (long)gridDim.x * blockDim.x;
    for (; i < n; i += st)
        dst[i] = f32 ? ((const float*)src)[i] : tofloat(((const bf16*)src)[i]);
}

__global__ void conv_dual_b16(const void* __restrict__ src, u16* __restrict__ dst,
                              long n, const int* __restrict__ flagp)
{
    bool f32 = (*flagp != 0);
    long i = (long)blockIdx.x * blockDim.x + threadIdx.x;
    long st = (long)gridDim.x * blockDim.x;
    for (; i < n; i += st)
        dst[i] = f32 ? f2b(((const float*)src)[i]) : ((const u16*)src)[i];
}

__global__ void conv_f32_b16(const float* __restrict__ src, u16* __restrict__ dst, long n)
{
    long i = (long)blockIdx.x * blockDim.x + threadIdx.x;
    long st = (long)gridDim.x * blockDim.x;
    for (; i < n; i += st) dst[i] = f2b(src[i]);
}

// ---------------- MFMA GEMM: C[M,N] = A[M,K] @ B[K,N], bf16 in, fp32 acc ----
// 64x64 tile, 256 thr = 4 waves (2x2), BK=32 (one mfma K). N%64==0, K%32==0.
// A layout per lane: A[m=lane&15][k=quad*8+j]; B[k=quad*8+j][n=lane&15];
// D: col=lane&15, row=quad*4+reg. Batch via blockIdx.z (sB, sC).
template<typename TC>
__global__ __launch_bounds__(256)
void gemm_mfma(const u16* __restrict__ A, int lda,
               const u16* __restrict__ B, int ldb,
               TC* __restrict__ C, int ldc,
               int M, int N, int K, long sB, long sC)
{
    __shared__ __align__(16) u16 As[64][40];   // [m][k], stride 80 B
    __shared__ __align__(16) u16 Bs[64][40];   // [n][k] (transposed)
    const u16* Bp = B + (long)blockIdx.z * sB;
    TC*        Cp = C + (long)blockIdx.z * sC;
    const int tid = threadIdx.x;
    const int lane = tid & 63, wave = tid >> 6;
    const int l15 = lane & 15, quad = lane >> 4;
    const int wm = (wave & 1) * 32, wn = (wave >> 1) * 32;
    const int row0 = blockIdx.x * 64, col0 = blockIdx.y * 64;
    const int arow = tid >> 2, ak = (tid & 3) * 8;
    const int bk = tid >> 3,  bn = (tid & 7) * 8;

    f32x4 acc[2][2];
#pragma unroll
    for (int i = 0; i < 2; i++)
#pragma unroll
        for (int j = 0; j < 2; j++)
#pragma unroll
            for (int r = 0; r < 4; r++) acc[i][j][r] = 0.f;

    for (int k0 = 0; k0 < K; k0 += 32) {
        {   // stage A: 64 rows x 32 k
            int r = row0 + arow;
            ushort4 v0 = {0,0,0,0}, v1 = {0,0,0,0};
            if (r < M) {
                const u16* p = A + (long)r * lda + k0 + ak;
                v0 = *(const ushort4*)p;
                v1 = *(const ushort4*)(p + 4);
            }
            *(ushort4*)&As[arow][ak]     = v0;
            *(ushort4*)&As[arow][ak + 4] = v1;
        }
        {   // stage B transposed: Bs[n][k]
            const u16* p = Bp + (long)(k0 + bk) * ldb + col0 + bn;
            ushort4 v0 = *(const ushort4*)p;
            ushort4 v1 = *(const ushort4*)(p + 4);
            Bs[bn + 0][bk] = v0.x; Bs[bn + 1][bk] = v0.y;
            Bs[bn + 2][bk] = v0.z; Bs[bn + 3][bk] = v0.w;
            Bs[bn + 4][bk] = v1.x; Bs[bn + 5][bk] = v1.y;
            Bs[bn + 6][bk] = v1.z; Bs[bn + 7][bk] = v1.w;
        }
        __syncthreads();
        short8 a0 = *(const short8*)&As[wm + l15][quad * 8];
        short8 a1 = *(const short8*)&As[wm + 16 + l15][quad * 8];
        short8 b0 = *(const short8*)&Bs[wn + l15][quad * 8];
        short8 b1 = *(const short8*)&Bs[wn + 16 + l15][quad * 8];
        acc[0][0] = __builtin_amdgcn_mfma_f32_16x16x32_bf16(a0, b0, acc[0][0], 0, 0, 0);
        acc[0][1] = __builtin_amdgcn_mfma_f32_16x16x32_bf16(a0, b1, acc[0][1], 0, 0, 0);
        acc[1][0] = __builtin_amdgcn_mfma_f32_16x16x32_bf16(a1, b0, acc[1][0], 0, 0, 0);
        acc[1][1] = __builtin_amdgcn_mfma_f32_16x16x32_bf16(a1, b1, acc[1][1], 0, 0, 0);
        __syncthreads();
    }
#pragma unroll
    for (int i = 0; i < 2; i++)
#pragma unroll
        for (int j = 0; j < 2; j++)
#pragma unroll
            for (int r = 0; r < 4; r++) {
                int row = row0 + wm + i * 16 + quad * 4 + r;
                int col = col0 + wn + j * 16 + l15;
                if (row < M) storec(&Cp[(long)row * ldc + col], acc[i][j][r]);
            }
}

// ---------------- vector GEMM (fp32, small) ---------------------------------
__global__ __launch_bounds__(256)
void gemm64(const float* __restrict__ A, int lda,
            const float* __restrict__ B, int ldb,
            float* __restrict__ C, int ldc,
            int M, int N, int K)
{
    __shared__ float As[16][68];
    __shared__ float Bs[16][68];
    const int tid = threadIdx.x;
    const int row0 = blockIdx.x * 64, col0 = blockIdx.y * 64;
    float acc[4][4];
#pragma unroll
    for (int i = 0; i < 4; i++)
#pragma unroll
        for (int j = 0; j < 4; j++) acc[i][j] = 0.f;
    const int ar = tid >> 2, ak = (tid & 3) * 4;
    const int bk = tid >> 4, bc = (tid & 15) * 4;
    const int ty4 = (tid >> 4) * 4, tx4 = (tid & 15) * 4;
    for (int k0 = 0; k0 < K; k0 += 16) {
        {
            int row = row0 + ar;
            float4 v = make_float4(0.f, 0.f, 0.f, 0.f);
            if (row < M) v = *(const float4*)(A + (long)row * lda + k0 + ak);
            As[ak + 0][ar] = v.x; As[ak + 1][ar] = v.y;
            As[ak + 2][ar] = v.z; As[ak + 3][ar] = v.w;
        }
        {
            int c = col0 + bc;
            float4 v = make_float4(0.f, 0.f, 0.f, 0.f);
            if (c < N) v = *(const float4*)(B + (long)(k0 + bk) * ldb + c);
            *(float4*)&Bs[bk][bc] = v;
        }
        __syncthreads();
#pragma unroll
        for (int k = 0; k < 16; k++) {
            float4 a = *(const float4*)&As[k][ty4];
            float4 b = *(const float4*)&Bs[k][tx4];
            acc[0][0] += a.x * b.x; acc[0][1] += a.x * b.y; acc[0][2] += a.x * b.z; acc[0][3] += a.x * b.w;
            acc[1][0] += a.y * b.x; acc[1][1] += a.y * b.y; acc[1][2] += a.y * b.z; acc[1][3] += a.y * b.w;
            acc[2][0] += a.z * b.x; acc[2][1] += a.z * b.y; acc[2][2] += a.z * b.z; acc[2][3] += a.z * b.w;
            acc[3][0] += a.w * b.x; acc[3][1] += a.w * b.y; acc[3][2] += a.w * b.z; acc[3][3] += a.w * b.w;
        }
        __syncthreads();
    }
    int c = col0 + tx4;
#pragma unroll
    for (int i = 0; i < 4; i++) {
        int r = row0 + ty4 + i;
        if (r < M && c < N)
            *(float4*)&C[(long)r * ldc + c] =
                make_float4(acc[i][0], acc[i][1], acc[i][2], acc[i][3]);
    }
}

// ---------------- utility / CSR build ---------------------------------------
__global__ void filli(int* p, long n, int v)
{
    long i = (long)blockIdx.x * blockDim.x + threadIdx.x;
    long st = (long)gridDim.x * blockDim.x;
    for (; i < n; i += st) p[i] = v;
}

__global__ void hist_int(const int* __restrict__ key, long n, int* __restrict__ h)
{
    long i = (long)blockIdx.x * blockDim.x + threadIdx.x;
    long st = (long)gridDim.x * blockDim.x;
    for (; i < n; i += st) atomicAdd(&h[key[i]], 1);
}

__global__ __launch_bounds__(1024)
void scan_bsum(const int* __restrict__ in, int n, int* __restrict__ btot)
{
    __shared__ int sh[1024];
    int tid = threadIdx.x;
    int i0 = blockIdx.x * 4096 + tid * 4;
    int s = 0;
#pragma unroll
    for (int t = 0; t < 4; t++) { int idx = i0 + t; s += (idx < n) ? in[idx] : 0; }
    sh[tid] = s;
    __syncthreads();
    for (int off = 512; off > 0; off >>= 1) {
        if (tid < off) sh[tid] += sh[tid + off];
        __syncthreads();
    }
    if (tid == 0) btot[blockIdx.x] = sh[0];
}

__global__ void scan_tiny(const int* __restrict__ btot, int nb, int* __restrict__ boff)
{
    if (threadIdx.x == 0) {
        int c = 0;
        for (int b = 0; b < nb; b++) { boff[b] = c; c += btot[b]; }
        boff[nb] = c;
    }
}

__global__ __launch_bounds__(1024)
void scan_final(const int* __restrict__ in, int n, const int* __restrict__ boff,
                int nb, int* __restrict__ out)
{
    __shared__ int buf[1024];
    int tid = threadIdx.x;
    int i0 = blockIdx.x * 4096 + tid * 4;
    int v[4]; int s = 0;
#pragma unroll
    for (int t = 0; t < 4; t++) {
        int idx = i0 + t;
        v[t] = (idx < n) ? in[idx] : 0;
        s += v[t];
    }
    buf[tid] = s;
    __syncthreads();
    for (int off = 1; off < 1024; off <<= 1) {
        int t = (tid >= off) ? buf[tid - off] : 0;
        __syncthreads();
        buf[tid] += t;
        __syncthreads();
    }
    int excl = buf[tid] - s + boff[blockIdx.x];
#pragma unroll
    for (int t = 0; t < 4; t++) {
        int idx = i0 + t;
        if (idx < n) out[idx] = excl;
        excl += v[t];
    }
    if (blockIdx.x == 0 && tid == 0) out[n] = boff[nb];
}

__global__ void bin_by(const int* __restrict__ key, long n,
                       const int* __restrict__ off, int* __restrict__ cursor,
                       int* __restrict__ bins)
{
    long i = (long)blockIdx.x * blockDim.x + threadIdx.x;
    long st = (long)gridDim.x * blockDim.x;
    for (; i < n; i += st) {
        int k = key[i];
        int pos = off[k] + atomicAdd(&cursor[k], 1);
        bins[pos] = (int)i;
    }
}

__global__ void dinv_from_deg(const int* __restrict__ deg, float* __restrict__ dinv, long n)
{
    long i = (long)blockIdx.x * blockDim.x + threadIdx.x;
    long st = (long)gridDim.x * blockDim.x;
    for (; i < n; i += st) dinv[i] = rsqrtf((float)(deg[i] + 1));
}

__global__ void kg_cnt(const int* __restrict__ dst, const int* __restrict__ et,
                       long E, int NKG, float* cnt)
{
    long i = (long)blockIdx.x * blockDim.x + threadIdx.x;
    long st = (long)gridDim.x * blockDim.x;
    for (; i < E; i += st) atomicAdd(&cnt[(long)et[i] * NKG + dst[i]], 1.0f);
}

__global__ void kg_enorm(const int* __restrict__ dst, const int* __restrict__ et,
                         const float* __restrict__ cnt, long E, int NKG,
                         float* __restrict__ en)
{
    long i = (long)blockIdx.x * blockDim.x + threadIdx.x;
    long st = (long)gridDim.x * blockDim.x;
    for (; i < E; i += st)
        en[i] = 1.0f / fmaxf(cnt[(long)et[i] * NKG + dst[i]], 1.0f);
}

__global__ void mol_enorm(const int* __restrict__ src, const int* __restrict__ dst,
                          const float* __restrict__ dinv, long E, float* __restrict__ en)
{
    long i = (long)blockIdx.x * blockDim.x + threadIdx.x;
    long st = (long)gridDim.x * blockDim.x;
    for (; i < E; i += st) en[i] = dinv[src[i]] * dinv[dst[i]];
}

// ---------------- batch-norm stats ------------------------------------------
__global__ __launch_bounds__(512)
void colstats_part(const float* __restrict__ X, int M, int N, int lgN, int G,
                   float* __restrict__ p1, float* __restrict__ p2)
{
    __shared__ float sh1[512], sh2[512];
    int tid = threadIdx.x;
    int col = tid & (N - 1);
    int grp = tid >> lgN;
    float s1 = 0.f, s2 = 0.f;
    for (long row = (long)blockIdx.x * G + grp; row < M; row += (long)gridDim.x * G) {
        float v = X[row * N + col];
        s1 += v; s2 += v * v;
    }
    sh1[tid] = s1; sh2[tid] = s2;
    __syncthreads();
    if (grp == 0) {
        for (int g = 1; g < G; g++) { s1 += sh1[col + (g << lgN)]; s2 += sh2[col + (g << lgN)]; }
        p1[blockIdx.x * N + col] = s1;
        p2[blockIdx.x * N + col] = s2;
    }
}

__global__ __launch_bounds__(512)
void colstats_part_b16(const u16* __restrict__ X, int M, int ld, int c0,
                       float* __restrict__ p1, float* __restrict__ p2)
{
    __shared__ float sh1[512], sh2[512];
    int tid = threadIdx.x;
    int col = tid & 63;
    int grp = tid >> 6;
    float s1 = 0.f, s2 = 0.f;
    for (long row = (long)blockIdx.x * 8 + grp; row < M; row += (long)gridDim.x * 8) {
        float v = b2f(X[row * ld + c0 + col]);
        s1 += v; s2 += v * v;
    }
    sh1[tid] = s1; sh2[tid] = s2;
    __syncthreads();
    if (grp == 0) {
        for (int g = 1; g < 8; g++) { s1 += sh1[col + (g << 6)]; s2 += sh2[col + (g << 6)]; }
        p1[blockIdx.x * 64 + col] = s1;
        p2[blockIdx.x * 64 + col] = s2;
    }
}

__global__ void colstats_reduce(const float* __restrict__ p1, const float* __restrict__ p2,
                                int nblk, int N, float invM,
                                float* __restrict__ s1o, float* __restrict__ s2o)
{
    int j = threadIdx.x;
    if (j >= N) return;
    float a = 0.f, c = 0.f;
    for (int b = 0; b < nblk; b += 4) {
        a += p1[(b + 0) * N + j] + p1[(b + 1) * N + j] + p1[(b + 2) * N + j] + p1[(b + 3) * N + j];
        c += p2[(b + 0) * N + j] + p2[(b + 1) * N + j] + p2[(b + 2) * N + j] + p2[(b + 3) * N + j];
    }
    float mean = a * invM;
    float var  = fmaxf(c * invM - mean * mean, 0.f);
    s1o[j] = mean;
    s2o[j] = rsqrtf(var + 1e-5f);
}

__global__ void bn_apply(float* X, long total, int mask,
                         const float* __restrict__ s1, const float* __restrict__ s2)
{
    long i = (long)blockIdx.x * blockDim.x + threadIdx.x;
    long st = (long)gridDim.x * blockDim.x;
    for (; i < total; i += st) {
        int j = (int)(i & mask);
        X[i] = fmaxf((X[i] - s1[j]) * s2[j], 0.f);
    }
}

// BN+ReLU, fp32 in place AND bf16 copy
__global__ void bn_apply_dual(float* __restrict__ X, u16* __restrict__ Xb, long total,
                              int mask, const float* __restrict__ s1,
                              const float* __restrict__ s2)
{
    long i = (long)blockIdx.x * blockDim.x + threadIdx.x;
    long st = (long)gridDim.x * blockDim.x;
    for (; i < total; i += st) {
        int j = (int)(i & mask);
        float y = fmaxf((X[i] - s1[j]) * s2[j], 0.f);
        X[i] = y;
        Xb[i] = f2b(y);
    }
}

// BN+ReLU in place on bf16 strided chunk [M,64] at X[n*ld + c0 + f]
__global__ void bn_apply_b16(u16* __restrict__ X, long total, int ld, int c0,
                             const float* __restrict__ s1, const float* __restrict__ s2)
{
    long i = (long)blockIdx.x * blockDim.x + threadIdx.x;
    long st = (long)gridDim.x * blockDim.x;
    for (; i < total; i += st) {
        long n = i >> 6;
        int  f = (int)(i & 63);
        u16* p = X + n * ld + c0 + f;
        *p = f2b(fmaxf((b2f(*p) - s1[f]) * s2[f], 0.f));
    }
}

// ---------------- CSR aggregation (no atomics) ------------------------------
// aggregate raw dual-dtype input [NM,64] -> bf16 out
__global__ __launch_bounds__(256)
void mol_agg_in(const void* __restrict__ X, const int* __restrict__ flagp,
                const float* __restrict__ dinv, const int* __restrict__ off,
                const int* __restrict__ bins, const int* __restrict__ src,
                const float* __restrict__ en, int NM, u16* __restrict__ out)
{
    bool f32 = (*flagp != 0);
    const float* Xf = (const float*)X;
    const u16*   Xh = (const u16*)X;
    int wid  = (int)(((long)blockIdx.x * 256 + threadIdx.x) >> 6);
    int lane = threadIdx.x & 63;
    if (wid >= NM) return;
    float dv = dinv[wid];
    float self = f32 ? Xf[(long)wid * 64 + lane] : b2f(Xh[(long)wid * 64 + lane]);
    float acc = self * dv * dv;
    int j = off[wid], j1 = off[wid + 1];
    for (; j < j1; j++) {
        int e = bins[j]; int s = src[e];
        float v = f32 ? Xf[(long)s * 64 + lane] : b2f(Xh[(long)s * 64 + lane]);
        acc += v * en[e];
    }
    out[(long)wid * 64 + lane] = f2b(acc);
}

// aggregate bf16 [NM,128] -> bf16 [NM,128]; lane covers cols 2l,2l+1
__global__ __launch_bounds__(256)
void mol_agg128(const u16* __restrict__ G, const float* __restrict__ dinv,
                const int* __restrict__ off, const int* __restrict__ bins,
                const int* __restrict__ src, const float* __restrict__ en,
                int NM, u16* __restrict__ out)
{
    int wid  = (int)(((long)blockIdx.x * 256 + threadIdx.x) >> 6);
    int lane = threadIdx.x & 63;
    if (wid >= NM) return;
    float dv = dinv[wid], dv2 = dv * dv;
    u32 u = *(const u32*)(G + (long)wid * 128 + 2 * lane);
    float a0 = b2f((u16)(u & 0xFFFF)) * dv2;
    float a1 = b2f((u16)(u >> 16)) * dv2;
    int j = off[wid], j1 = off[wid + 1];
    for (; j < j1; j++) {
        int e = bins[j]; int s = src[e]; float n = en[e];
        u32 v = *(const u32*)(G + (long)s * 128 + 2 * lane);
        a0 += b2f((u16)(v & 0xFFFF)) * n;
        a1 += b2f((u16)(v >> 16)) * n;
    }
    u32 o = (u32)f2b(a0) | ((u32)f2b(a1) << 16);
    *(u32*)(out + (long)wid * 128 + 2 * lane) = o;
}

// RGCN gather: hr bf16 [8,NKG,128] -> out[d, c0 + 2l(+1)] +=
__global__ __launch_bounds__(256)
void rgcn_agg128(const u16* __restrict__ hr, const int* __restrict__ off,
                 const int* __restrict__ bins, const int* __restrict__ src,
                 const int* __restrict__ et, const float* __restrict__ en,
                 int NKG, float* __restrict__ out, int ldout, int c0)
{
    int wid  = (int)(((long)blockIdx.x * 256 + threadIdx.x) >> 6);
    int lane = threadIdx.x & 63;
    if (wid >= NKG) return;
    float a0 = 0.f, a1 = 0.f;
    int j = off[wid], j1 = off[wid + 1];
    for (; j + 1 < j1; j += 2) {
        int e0 = bins[j], e1 = bins[j + 1];
        int r0 = et[e0], s0 = src[e0];
        int r1 = et[e1], s1 = src[e1];
        float n0 = en[e0], n1 = en[e1];
        u32 u0 = *(const u32*)(hr + ((long)r0 * NKG + s0) * 128 + 2 * lane);
        u32 u1 = *(const u32*)(hr + ((long)r1 * NKG + s1) * 128 + 2 * lane);
        a0 += b2f((u16)(u0 & 0xFFFF)) * n0 + b2f((u16)(u1 & 0xFFFF)) * n1;
        a1 += b2f((u16)(u0 >> 16)) * n0 + b2f((u16)(u1 >> 16)) * n1;
    }
    if (j < j1) {
        int e = bins[j];
        u32 u0 = *(const u32*)(hr + ((long)et[e] * NKG + src[e]) * 128 + 2 * lane);
        float n0 = en[e];
        a0 += b2f((u16)(u0 & 0xFFFF)) * n0;
        a1 += b2f((u16)(u0 >> 16)) * n0;
    }
    float2* o = (float2*)(out + (long)wid * ldout + c0 + 2 * lane);
    float2 v = *o; v.x += a0; v.y += a1; *o = v;
}

// mean-pool bf16 chunk [NM,64] with fused BN+ReLU
__global__ __launch_bounds__(256)
void pool_b16(const u16* __restrict__ g, const int* __restrict__ off,
              const int* __restrict__ bins, int ND,
              const float* __restrict__ s1, const float* __restrict__ s2,
              float* __restrict__ gout, int c0)
{
    int wid  = (int)(((long)blockIdx.x * 256 + threadIdx.x) >> 6);
    int lane = threadIdx.x & 63;
    if (wid >= ND) return;
    float m = s1[lane], r = s2[lane];
    int j0 = off[wid], j1 = off[wid + 1];
    float acc = 0.f;
    for (int j = j0; j < j1; j++)
        acc += fmaxf((b2f(g[(long)bins[j] * 64 + lane]) - m) * r, 0.f);
    gout[(long)wid * 256 + c0 + lane] = acc / fmaxf((float)(j1 - j0), 1.0f);
}

// ---------------- attention fusion ------------------------------------------
__global__ void attention_fuse(const float* __restrict__ go, const float* __restrict__ fpv,
                               const float* __restrict__ W1, const float* __restrict__ B1,
                               const float* __restrict__ W2,
                               float* __restrict__ emb, float* __restrict__ beta_out)
{
    int d = blockIdx.x;
    int t = threadIdx.x;
    __shared__ float z[2][256];
    __shared__ float red[128];
    for (int c = t; c < 256; c += 128) {
        z[0][c] = go[(long)d * 256 + c];
        z[1][c] = fpv[(long)d * 256 + c];
    }
    __syncthreads();
    float s[2];
    for (int v = 0; v < 2; v++) {
        float acc = B1[t];
        for (int k = 0; k < 256; k++) acc += z[v][k] * W1[k * 128 + t];
        red[t] = tanhf(acc) * W2[t];
        __syncthreads();
        for (int off = 64; off > 0; off >>= 1) {
            if (t < off) red[t] += red[t + off];
            __syncthreads();
        }
        s[v] = red[0];
        __syncthreads();
    }
    float m = fmaxf(s[0], s[1]);
    float e0 = expf(s[0] - m), e1 = expf(s[1] - m);
    float inv = 1.0f / (e0 + e1);
    float b0 = e0 * inv, b1 = e1 * inv;
    for (int c = t; c < 256; c += 128)
        emb[(long)d * 256 + c] = b0 * z[0][c] + b1 * z[1][c];
    if (t == 0) {
        beta_out[d * 2 + 0] = b0;
        beta_out[d * 2 + 1] = b1;
    }
}

// ---------------- final linear + log_softmax, fused BN on x4 ----------------
__global__ void logits_out_bn(const float* __restrict__ x4,
                              const float* __restrict__ s1, const float* __restrict__ s2,
                              const float* __restrict__ w, const float* __restrict__ b,
                              float* __restrict__ out, int NKG)
{
    int i = blockIdx.x * blockDim.x + threadIdx.x;
    if (i >= NKG) return;
    float a0 = b[0], a1 = b[1];
    for (int k = 0; k < 64; k++) {
        float v = fmaxf((x4[(long)i * 64 + k] - s1[k]) * s2[k], 0.f);
        a0 += v * w[k * 2 + 0];
        a1 += v * w[k * 2 + 1];
    }
    float m = fmaxf(a0, a1);
    float lse = m + logf(expf(a0 - m) + expf(a1 - m));
    out[i * 2 + 0] = a0 - lse;
    out[i * 2 + 1] = a1 - lse;
}

// ============================================================================
extern "C" void kernel_launch(void* const* d_in, const int* in_sizes, int n_in,
                              void* d_out, int out_size, void* d_ws, size_t ws_size,
                              hipStream_t stream)
{
    (void)in_sizes; (void)n_in; (void)out_size; (void)ws_size;
    const int ND = 4096, NM = 131072, NKG = 9510, NGENE = 5414;
    const long EM = 524288, EK = 524288;

    const void* fp_data = d_in[0];
    const void* mol_x   = d_in[1];
    const int*  mol_batch = (const int*)d_in[2];
    const int*  mol_ei  = (const int*)d_in[3];
    const int*  kg_ei   = (const int*)d_in[4];
    const int*  kg_et   = (const int*)d_in[5];

    const int* mol_src = mol_ei;
    const int* mol_dst = mol_ei + EM;
    const int* kg_src  = kg_ei;
    const int* kg_dst  = kg_ei + EK;

    float* out_ls   = (float*)d_out;          // [9510,2] fp32
    float* out_beta = (float*)d_out + 19020;  // [4096,2,1] fp32

    // ---- workspace carve (~117 MB) ----
    char* wp = (char*)d_ws;
    auto carve = [&](size_t bytes) { char* p = wp; wp += (bytes + 255) & ~(size_t)255; return p; };
    float* stats = (float*)carve(4096);
    int*   flag  = (int*)carve(256);
    float* dinv  = (float*)carve((size_t)NM * 4);
    float* enM   = (float*)carve((size_t)EM * 4);
    float* enK   = (float*)carve((size_t)EK * 4);
    float* part1 = (float*)carve((size_t)64 * 512 * 4);
    float* part2 = (float*)carve((size_t)64 * 512 * 4);
    int*   sbt   = (int*)carve(256);
    int*   sbo   = (int*)carve(256);
    float* Wpool = (float*)carve((size_t)1630000 * 4);     // fp32 weights
    u16*   WpoolB= (u16*)carve((size_t)1630000 * 2);       // bf16 weights
    float* fpb   = (float*)carve((size_t)ND * 256 * 4);
    float* gout  = (float*)carve((size_t)ND * 256 * 4);
    // zero-span
    char*  z0    = wp;
    float* cntK  = (float*)carve((size_t)8 * NKG * 4);
    int* mdeg = (int*)carve((size_t)NM * 4);
    int* mcur = (int*)carve((size_t)NM * 4);
    int* kdeg = (int*)carve((size_t)NKG * 4);
    int* kcur = (int*)carve((size_t)NKG * 4);
    int* pdeg = (int*)carve((size_t)ND * 4);
    int* pcur = (int*)carve((size_t)ND * 4);
    char*  z1    = wp;
    int* moff = (int*)carve((size_t)(NM + 1) * 4);
    int* mbins= (int*)carve((size_t)EM * 4);
    int* koff = (int*)carve((size_t)(NKG + 1) * 4);
    int* kbins= (int*)carve((size_t)EK * 4);
    int* poff = (int*)carve((size_t)(ND + 1) * 4);
    int* pbins= (int*)carve((size_t)NM * 4);
    char*  REG1  = carve((size_t)NM * 128 * 2);            // 33.6 MB
    char*  REG2  = carve((size_t)NM * 128 * 2);            // 33.6 MB
    u16*   HB    = (u16*)carve((size_t)NM * 64 * 2);       // 16.8 MB

    // phase views
    float* fp1 = (float*)REG1;                 // fp: [4096,512] f32
    u16*   G1  = (u16*)REG1;                   // mol: [NM,128] bf16
    float* xkg = (float*)REG1;                 // rgcn: x chain f32
    float* x2  = xkg + (size_t)NKG * 256;
    float* x3  = x2  + (size_t)NKG * 256;
    float* x4  = x3  + (size_t)NKG * 128;
    u16*   Xfb = (u16*)REG2;                   // fp: [4096,1024] bf16
    u16*   G1A = (u16*)REG2;                   // mol: [NM,128] bf16 aggregated
    u16*   HR  = (u16*)REG2;                   // rgcn: [8,NKG,128] bf16
    u16*   xb  = HR + (size_t)8 * NKG * 128;   // [NKG,256] bf16
    u16*   x2b = xb + (size_t)NKG * 256;       // [NKG,256] bf16
    u16*   fp1b = HB;                          // fp: [4096,512] bf16
    u16*   Xagg = HB;                          // mol L1: [NM,64] bf16

    // ---- dtype detect + weight conversion (fp32 + bf16 pools) ----
    zero_int<<<1, 1, 0, stream>>>(flag);
    detect_f32<<<1024, 256, 0, stream>>>((const u16*)fp_data, (long)ND * 1024, flag);
    ConvTab tab;
    const int widx[14] = {6, 8, 10, 12, 14, 15, 16, 18, 19, 21, 22, 24, 26, 27};
    const int wn[14]   = {1024*512, 512*256, 64*128, 128*256, 256*128, 128, 128,
                          8*256*256, 256*256, 8*256*128, 256*128, 128*64, 64*2, 2};
    float* wf[14]; u16* wb[14];
    {
        size_t o = 0;
        for (int i = 0; i < 14; i++) {
            tab.src[i]  = d_in[widx[i]];
            tab.dst[i]  = Wpool + o;
            tab.dstB[i] = WpoolB + o;
            tab.n[i]    = wn[i];
            wf[i] = Wpool + o; wb[i] = WpoolB + o;
            o += (size_t)wn[i];
        }
    }
    conv_all<<<dim3(32, 14), 256, 0, stream>>>(tab, flag);
    u16 *fp_w1b = wb[0], *fp_w2b = wb[1], *gcn_w1b = wb[2], *gcn_w2b = wb[3];
    float *att_w1c = wf[4], *att_b1c = wf[5], *att_w2c = wf[6];
    u16 *rg_w1b = wb[7], *rg_root1b = wb[8], *rg_w2b = wb[9], *rg_root2b = wb[10];
    float *lin1_wc = wf[11], *lin2_wc = wf[12], *lin2_bc = wf[13];

    // ---- CSR builds ----
    filli<<<512, 256, 0, stream>>>((int*)z0, (long)(z1 - z0) / 4, 0);
    auto scan = [&](const int* deg, int* off, int n) {
        int nb = divup(n, 4096);
        scan_bsum<<<nb, 1024, 0, stream>>>(deg, n, sbt);
        scan_tiny<<<1, 64, 0, stream>>>(sbt, nb, sbo);
        scan_final<<<nb, 1024, 0, stream>>>(deg, n, sbo, nb, off);
    };
    hist_int<<<2048, 256, 0, stream>>>(mol_dst, EM, mdeg);
    scan(mdeg, moff, NM);
    bin_by<<<2048, 256, 0, stream>>>(mol_dst, EM, moff, mcur, mbins);
    dinv_from_deg<<<512, 256, 0, stream>>>(mdeg, dinv, NM);
    mol_enorm<<<1024, 256, 0, stream>>>(mol_src, mol_dst, dinv, EM, enM);

    hist_int<<<2048, 256, 0, stream>>>(kg_dst, EK, kdeg);
    scan(kdeg, koff, NKG);
    bin_by<<<2048, 256, 0, stream>>>(kg_dst, EK, koff, kcur, kbins);
    kg_cnt<<<2048, 256, 0, stream>>>(kg_dst, kg_et, EK, NKG, cntK);
    kg_enorm<<<1024, 256, 0, stream>>>(kg_dst, kg_et, cntK, EK, NKG, enK);

    hist_int<<<512, 256, 0, stream>>>(mol_batch, NM, pdeg);
    scan(pdeg, poff, ND);
    bin_by<<<512, 256, 0, stream>>>(mol_batch, NM, poff, pcur, pbins);

    // ---- BN helpers ----
    auto bn_stats = [&](const float* X, int M, int N, int lgN) {
        colstats_part<<<64, 512, 0, stream>>>(X, M, N, lgN, 512 >> lgN, part1, part2);
        colstats_reduce<<<1, N, 0, stream>>>(part1, part2, 64, N, 1.0f / M,
                                             stats, stats + 512);
    };
    auto bn_stats_b16 = [&](const u16* X, int M, int ld, int c0) {
        colstats_part_b16<<<64, 512, 0, stream>>>(X, M, ld, c0, part1, part2);
        colstats_reduce<<<1, 64, 0, stream>>>(part1, part2, 64, 64, 1.0f / M,
                                              stats, stats + 512);
    };

    // ---------- fingerprint MLP branch (MFMA) ----------
    conv_dual_b16<<<2048, 256, 0, stream>>>(fp_data, Xfb, (long)ND * 1024, flag);
    gemm_mfma<float><<<dim3(64, 8, 1), 256, 0, stream>>>(
        Xfb, 1024, fp_w1b, 512, fp1, 512, ND, 512, 1024, 0, 0);
    bn_stats(fp1, ND, 512, 9);
    bn_apply_dual<<<2048, 256, 0, stream>>>(fp1, fp1b, (long)ND * 512, 511,
                                            stats, stats + 512);
    gemm_mfma<float><<<dim3(64, 4, 1), 256, 0, stream>>>(
        fp1b, 512, fp_w2b, 256, fpb, 256, ND, 256, 512, 0, 0);
    bn_stats(fpb, ND, 256, 8);
    bn_apply<<<2048, 256, 0, stream>>>(fpb, (long)ND * 256, 255, stats, stats + 512);

    // ---------- mol GCN layer 1: aggregate-then-GEMM (reordered) ------------
    mol_agg_in<<<32768, 256, 0, stream>>>(mol_x, flag, dinv, moff, mbins, mol_src,
                                          enM, NM, Xagg);
    gemm_mfma<u16><<<dim3(2048, 2, 1), 256, 0, stream>>>(
        Xagg, 64, gcn_w1b, 128, G1, 128, NM, 128, 64, 0, 0);
    for (int c0 = 0; c0 < 128; c0 += 64) {
        bn_stats_b16(G1, NM, 128, c0);
        bn_apply_b16<<<8192, 256, 0, stream>>>(G1, (long)NM * 64, 128, c0,
                                               stats, stats + 512);
    }

    // ---------- mol GCN layer 2: aggregate-then-GEMM + BN + pool ------------
    mol_agg128<<<32768, 256, 0, stream>>>(G1, dinv, moff, mbins, mol_src, enM, NM, G1A);
    for (int c0 = 0; c0 < 256; c0 += 64) {
        gemm_mfma<u16><<<dim3(2048, 1, 1), 256, 0, stream>>>(
            G1A, 128, gcn_w2b + c0, 256, HB, 64, NM, 64, 128, 0, 0);
        bn_stats_b16(HB, NM, 64, 0);
        pool_b16<<<1024, 256, 0, stream>>>(HB, poff, pbins, ND,
                                           stats, stats + 512, gout, c0);
    }

    // ---------- attention fusion ----------
    attention_fuse<<<ND, 128, 0, stream>>>(gout, fpb, att_w1c, att_b1c, att_w2c,
                                           xkg, out_beta);
    conv_in<<<512, 256, 0, stream>>>(d_in[17], xkg + (long)ND * 256,
                                     (long)NGENE * 256, flag);
    conv_f32_b16<<<1024, 256, 0, stream>>>(xkg, xb, (long)NKG * 256);

    // ---------- RGCN layer 1 (256 -> 256) ----------
    gemm_mfma<float><<<dim3(divup(NKG, 64), 4, 1), 256, 0, stream>>>(
        xb, 256, rg_root1b, 256, x2, 256, NKG, 256, 256, 0, 0);
    for (int c0 = 0; c0 < 256; c0 += 128) {
        gemm_mfma<u16><<<dim3(divup(NKG, 64), 2, 8), 256, 0, stream>>>(
            xb, 256, rg_w1b + c0, 256, HR, 128, NKG, 128, 256,
            (long)256 * 256, (long)NKG * 128);
        rgcn_agg128<<<2378, 256, 0, stream>>>(HR, koff, kbins, kg_src, kg_et, enK,
                                              NKG, x2, 256, c0);
    }
    bn_stats(x2, NKG, 256, 8);
    bn_apply_dual<<<2048, 256, 0, stream>>>(x2, x2b, (long)NKG * 256, 255,
                                            stats, stats + 512);

    // ---------- RGCN layer 2 (256 -> 128) ----------
    gemm_mfma<float><<<dim3(divup(NKG, 64), 2, 1), 256, 0, stream>>>(
        x2b, 256, rg_root2b, 128, x3, 128, NKG, 128, 256, 0, 0);
    gemm_mfma<u16><<<dim3(divup(NKG, 64), 2, 8), 256, 0, stream>>>(
        x2b, 256, rg_w2b, 128, HR, 128, NKG, 128, 256,
        (long)256 * 128, (long)NKG * 128);
    rgcn_agg128<<<2378, 256, 0, stream>>>(HR, koff, kbins, kg_src, kg_et, enK,
                                          NKG, x3, 128, 0);
    bn_stats(x3, NKG, 128, 7);
    bn_apply<<<2048, 256, 0, stream>>>(x3, (long)NKG * 128, 127, stats, stats + 512);

    // ---------- classifier head ----------
    gemm64<<<dim3(divup(NKG, 64), 1, 1), 256, 0, stream>>>(
        x3, 128, lin1_wc, 64, x4, 64, NKG, 64, 128);
    bn_stats(x4, NKG, 64, 6);
    logits_out_bn<<<divup(NKG, 256), 256, 0, stream>>>(x4, stats, stats + 512,
                                                       lin2_wc, lin2_bc, out_ls, NKG);
}